// Round 15
// baseline (216.644 us; speedup 1.0000x reference)
//
#include <hip/hip_runtime.h>

// ---------------------------------------------------------------------------
// GCN pipeline: CNN(conv3x3+relu+pool2x2+FC1+FC2) -> SAGE(mean) -> SAGE(mean)
// Round 15: (1) K-split x8 (grid 625x8: qq=y&3, ph-half=y>>2, 5 quarters per
// block) -> block-granularity tail 3d -> 2.5d; (2) sage2 self-projection
// folded into sage1_fused (self16 = s2_b + h1@s2_self computed while h1 row
// is in LDS; h1 global buffer eliminated). Numerics identical.
// ---------------------------------------------------------------------------

typedef __attribute__((ext_vector_type(8)))  short bf16x8;
typedef __attribute__((ext_vector_type(4)))  float f32x4;
typedef __attribute__((ext_vector_type(16))) float f32x16;

__device__ __forceinline__ unsigned short f2bf(float v) {
    union { float f; unsigned int u; } x; x.f = v;
    unsigned int r = x.u + 0x7FFFu + ((x.u >> 16) & 1u);  // RNE
    return (unsigned short)(r >> 16);
}
__device__ __forceinline__ float bf2f(unsigned short b) {
    union { float f; unsigned int u; } x; x.u = ((unsigned int)b) << 16;
    return x.f;
}
__device__ __forceinline__ unsigned cvtpk(float a, float b) {   // low16=bf(a), high16=bf(b)
    unsigned r;
    asm("v_cvt_pk_bf16_f32 %0, %1, %2" : "=v"(r) : "v"(a), "v"(b));
    return r;
}
__device__ __forceinline__ float lo2f(unsigned p) { union { unsigned u; float f; } x; x.u = p << 16; return x.f; }
__device__ __forceinline__ float hi2f(unsigned p) { union { unsigned u; float f; } x; x.u = p & 0xffff0000u; return x.f; }
__device__ __forceinline__ void split_pair(float a, float b, unsigned& hp, unsigned& lp) {
    hp = cvtpk(a, b);
    lp = cvtpk(a - lo2f(hp), b - hi2f(hp));
}

__global__ __launch_bounds__(256) void zero_ws(float* __restrict__ ws, int count) {
    int i = blockIdx.x * 256 + threadIdx.x;
    if (i < count) ws[i] = 0.0f;
}

// ---------------------------------------------------------------------------
// w1 prep (grid 320): fragment-ready bf16 hi/lo image per quarter (ph,qq).
// ---------------------------------------------------------------------------
__global__ __launch_bounds__(256) void w1_prep_v3(
    const float* __restrict__ w1, unsigned char* __restrict__ w1f)
{
    int gu = blockIdx.x * 256 + threadIdx.x;   // 0..81919
    const int quarter = gu >> 11;
    const int u = gu & 2047;
    const int ph = quarter >> 2, qq = quarter & 3;
    const int ks   = u >> 8;
    const int jh   = (u >> 7) & 1;
    const int part = (u >> 6) & 1;
    const int lane = u & 63;
    const int j    = jh * 16 + (lane & 15);
    const int c    = ks * 4 + (lane >> 4);
    const int k0   = c * 320 + ph * 32 + qq * 8;
    unsigned short v[8];
#pragma unroll
    for (int i = 0; i < 8; ++i) {
        float x = w1[(size_t)(k0 + i) * 32 + j];
        unsigned short h = f2bf(x);
        v[i] = part ? f2bf(x - bf2f(h)) : h;
    }
    *(uint4*)(w1f + (size_t)quarter * 32768 + (size_t)u * 16) = *(const uint4*)v;
}

// ---------------------------------------------------------------------------
// Fused CNN v15: 16 nodes/block, 256 threads, grid (625, 8).
// blockIdx.y: qq = y&3 (column slice), phlo = (y>>2)*5 (ph half) -> 5
// quarters per block; halves block duration for tail-quantization gain.
// LDS: convA 18KB (swz byte ^= ((byte>>7)&3)<<4) + fc1A 16KB single buffer
// (swz byte ^= ((byte>>8)&7)<<4) = 34.8KB -> 4 blocks/CU. 2 barriers/quarter.
// ---------------------------------------------------------------------------
__global__ __launch_bounds__(256, 4) void cnn_fused_v15(
    const float* __restrict__ feat,
    const float* __restrict__ conv_w, const float* __restrict__ conv_b,
    const unsigned char* __restrict__ w1f,
    float* __restrict__ h_fc1)
{
    __shared__ __align__(16) unsigned char convA[18432];
    __shared__ __align__(16) unsigned char fc1A[16384];   // single buffer

    const int t = threadIdx.x;
    const int wv = t >> 6;            // 0..3
    const int lane = t & 63;
    const int base = blockIdx.x * 16;
    const int qq = blockIdx.y & 3;          // column slice 0..3
    const int phlo = (blockIdx.y >> 2) * 5; // ph range [phlo, phlo+5)

    const int nn  = lane >> 4;
    const int pwl = lane & 7;
    const int aa  = (lane >> 3) & 1;
    const float* featn = feat + (size_t)(base + wv * 4 + nn) * 1280;

    const int pw = qq * 8 + pwl;      // fixed pooled col
    const int c0 = 2 * pw - 1;        // fixed input col window c0..c0+3
    const bool cv0 = (c0 >= 0);
    const bool cv3 = (c0 + 3 < 64);

    const int cch = lane & 31;
    const int ckg = lane >> 5;
    const int rowr = lane & 31;
    unsigned rsw = (unsigned)(rowr << 4); rsw ^= ((rsw >> 7) & 3u) << 4;

    // conv weight fragments; k=9 carries the bias (A-side k9 input is 1.0)
    bf16x8 cbh, cbl;
    {
        union { unsigned short u[8]; bf16x8 v; } H, L;
#pragma unroll
        for (int i = 0; i < 8; ++i) {
            int k = ckg * 8 + i;
            float x = (k < 9) ? conv_w[cch * 9 + k] : (k == 9 ? conv_b[cch] : 0.0f);
            unsigned short h = f2bf(x);
            H.u[i] = h; L.u[i] = f2bf(x - bf2f(h));
        }
        cbh = H.v; cbl = L.v;
    }

    const int nfr = lane & 15;

    f32x4 acc0 = {0.f, 0.f, 0.f, 0.f};
    f32x4 acc1 = {0.f, 0.f, 0.f, 0.f};
    const f32x16 czero = {};    // hoisted zero C-operand

    float f0[4], f1[4], f2[4];
    auto load_row = [&](int r, float* o) {
        bool rv = (r >= 0) && (r < 20);
        const float* rp = featn + (rv ? r : 0) * 64;
        float2 m = *(const float2*)(rp + c0 + 1);    // c0+1 = 2pw: 8B-aligned, in-bounds
        float v0 = rp[cv0 ? c0 : 0];
        float v3 = rp[cv3 ? (c0 + 3) : 0];
        o[0] = (rv && cv0) ? v0 : 0.f;
        o[1] = rv ? m.x : 0.f;
        o[2] = rv ? m.y : 0.f;
        o[3] = (rv && cv3) ? v3 : 0.f;
    };

    load_row(2 * phlo - 1 + aa, f0);
    load_row(2 * phlo + aa,     f1);
    load_row(2 * phlo + 1 + aa, f2);

#pragma unroll 1
    for (int ph = phlo; ph < phlo + 5; ++ph) {
        const int quarter = ph * 4 + qq;
        unsigned char* fbuf = fc1A;

        // ---- (1) FC1 B-frags from global (L2); consumed in phase 4
        const unsigned char* wq = w1f + (size_t)quarter * 32768;
        bf16x8 bF[2][2][2];
#pragma unroll
        for (int si = 0; si < 2; ++si) {
            const int ks = wv + si * 4;
#pragma unroll
            for (int jh = 0; jh < 2; ++jh)
#pragma unroll
                for (int part = 0; part < 2; ++part)
                    bF[si][jh][part] = *(const bf16x8*)(
                        wq + (size_t)((((ks * 2 + jh) * 2 + part)) << 10) + lane * 16);
        }

        // ---- (2) split current rows -> convA + compact tap8
        {
            unsigned P[3][2], Q[3][2];
            split_pair(f0[0], f0[1], P[0][0], Q[0][0]);
            split_pair(f0[2], f0[3], P[0][1], Q[0][1]);
            split_pair(f1[0], f1[1], P[1][0], Q[1][0]);
            split_pair(f1[2], f1[3], P[1][1], Q[1][1]);
            split_pair(f2[0], f2[1], P[2][0], Q[2][0]);
            split_pair(f2[2], f2[3], P[2][1], Q[2][1]);

            const int r0 = pwl * 4 + aa * 2, r1 = r0 + 1;
            unsigned b0 = (unsigned)(r0 << 4); b0 ^= ((b0 >> 7) & 3u) << 4;
            unsigned b1 = (unsigned)(r1 << 4); b1 ^= ((b1 >> 7) & 3u) << 4;
            unsigned char* abw = convA + ((wv * 4 + nn) << 10);
            uint4 H0 = make_uint4(P[0][0],
                                  __builtin_amdgcn_perm(P[1][0], P[0][1], 0x05040100u),
                                  __builtin_amdgcn_perm(P[1][1], P[1][0], 0x05040302u),
                                  P[2][0]);
            uint4 H1 = make_uint4(__builtin_amdgcn_perm(P[0][1], P[0][0], 0x05040302u),
                                  __builtin_amdgcn_perm(P[1][0], P[0][1], 0x07060302u),
                                  P[1][1],
                                  __builtin_amdgcn_perm(P[2][1], P[2][0], 0x05040302u));
            uint4 L0 = make_uint4(Q[0][0],
                                  __builtin_amdgcn_perm(Q[1][0], Q[0][1], 0x05040100u),
                                  __builtin_amdgcn_perm(Q[1][1], Q[1][0], 0x05040302u),
                                  Q[2][0]);
            uint4 L1 = make_uint4(__builtin_amdgcn_perm(Q[0][1], Q[0][0], 0x05040302u),
                                  __builtin_amdgcn_perm(Q[1][0], Q[0][1], 0x07060302u),
                                  Q[1][1],
                                  __builtin_amdgcn_perm(Q[2][1], Q[2][0], 0x05040302u));
            *(uint4*)(abw + b0)       = H0;
            *(uint4*)(abw + b1)       = H1;
            *(uint4*)(abw + 512 + b0) = L0;
            *(uint4*)(abw + 512 + b1) = L1;
            unsigned wr0 = __builtin_amdgcn_perm(Q[2][1], P[2][1], 0x05040100u);
            unsigned wr1 = __builtin_amdgcn_perm(Q[2][1], P[2][1], 0x07060302u);
            *(uint2*)(convA + 16384 + (((wv * 4 + nn) * 32 + r0) << 2)) = make_uint2(wr0, wr1);
        }

        // ---- (2b) rotate window + prefetch next ph's two new rows
        if (ph < phlo + 4) {
#pragma unroll
            for (int j = 0; j < 4; ++j) f0[j] = f2[j];
            load_row(2 * ph + 2 + aa, f1);
            load_row(2 * ph + 3 + aa, f2);
        }

        // ---- (3) conv MFMA + in-lane pool + repack into fc1A
#pragma unroll
        for (int nn2 = 0; nn2 < 4; ++nn2) {
            bf16x8 a_h, a_l;
            if (ckg == 0) {
                const unsigned char* ab = convA + ((wv * 4 + nn2) << 10);
                a_h = *(const bf16x8*)(ab + rsw);
                a_l = *(const bf16x8*)(ab + 512 + rsw);
            } else {
                unsigned cw = *(const unsigned*)(convA + 16384 + (((wv * 4 + nn2) * 32 + rowr) << 2));
                // k=8: tap8 (hi/lo); k=9: constant 1.0 (bias tap; bf16(1.0)=0x3F80)
                a_h = (bf16x8){(short)(cw & 0xffffu), (short)0x3F80, 0, 0, 0, 0, 0, 0};
                a_l = (bf16x8){(short)(cw >> 16),     0,             0, 0, 0, 0, 0, 0};
            }
            f32x16 ca;
            ca = __builtin_amdgcn_mfma_f32_32x32x16_bf16(a_l, cbh, czero, 0, 0, 0);
            ca = __builtin_amdgcn_mfma_f32_32x32x16_bf16(a_h, cbl, ca, 0, 0, 0);
            ca = __builtin_amdgcn_mfma_f32_32x32x16_bf16(a_h, cbh, ca, 0, 0, 0);

            // bias already inside ca via k=9 tap; max(a+c,b+c)=max(a,b)+c
            float pv0 = fmaxf(fmaxf(fmaxf(ca[0],  ca[1]),  fmaxf(ca[2],  ca[3])),  0.f);
            float pv1 = fmaxf(fmaxf(fmaxf(ca[4],  ca[5]),  fmaxf(ca[6],  ca[7])),  0.f);
            float pv2 = fmaxf(fmaxf(fmaxf(ca[8],  ca[9]),  fmaxf(ca[10], ca[11])), 0.f);
            float pv3 = fmaxf(fmaxf(fmaxf(ca[12], ca[13]), fmaxf(ca[14], ca[15])), 0.f);

            unsigned ha, la, hb, lb;
            split_pair(pv0, pv1, ha, la);
            split_pair(pv2, pv3, hb, lb);
            unsigned pha = (unsigned)__shfl_xor((int)ha, 32);
            unsigned phb = (unsigned)__shfl_xor((int)hb, 32);
            unsigned pla = (unsigned)__shfl_xor((int)la, 32);
            unsigned plb = (unsigned)__shfl_xor((int)lb, 32);
            bool hih = (lane < 32);
            unsigned q0v = hih ? pha : la;
            unsigned q1v = hih ? ha  : pla;
            unsigned q2v = hih ? phb : lb;
            unsigned q3v = hih ? hb  : plb;
            unsigned w0  = __builtin_amdgcn_perm(q0v, q1v, 0x05040100u);
            unsigned w1v = __builtin_amdgcn_perm(q0v, q1v, 0x07060302u);
            unsigned w2v = __builtin_amdgcn_perm(q2v, q3v, 0x05040100u);
            unsigned w3v = __builtin_amdgcn_perm(q2v, q3v, 0x07060302u);
            const int nloc = wv * 4 + nn2;
            const int pS = hih ? 0 : 1;
            const int ksW = cch >> 2, kgW = cch & 3;
            unsigned byteW = (unsigned)((((pS * 8 + ksW) * 64) + kgW * 16 + nloc) << 4);
            byteW ^= ((byteW >> 8) & 7u) << 4;
            *(uint4*)(fbuf + byteW) = make_uint4(w0, w1v, w2v, w3v);
        }

        __syncthreads();   // fc1A writes visible to all waves

        // ---- (4) FC1 MFMA: wave wv handles ksteps {wv, wv+4}
#pragma unroll
        for (int si = 0; si < 2; ++si) {
            const int ks = wv + si * 4;
            unsigned bH = (unsigned)(((0 * 8 + ks) << 10) + lane * 16); bH ^= ((bH >> 8) & 7u) << 4;
            unsigned bL = (unsigned)(((1 * 8 + ks) << 10) + lane * 16); bL ^= ((bL >> 8) & 7u) << 4;
            bf16x8 fa_h = *(const bf16x8*)(fbuf + bH);
            bf16x8 fa_l = *(const bf16x8*)(fbuf + bL);
            acc0 = __builtin_amdgcn_mfma_f32_16x16x32_bf16(fa_l, bF[si][0][0], acc0, 0, 0, 0);
            acc0 = __builtin_amdgcn_mfma_f32_16x16x32_bf16(fa_h, bF[si][0][1], acc0, 0, 0, 0);
            acc0 = __builtin_amdgcn_mfma_f32_16x16x32_bf16(fa_h, bF[si][0][0], acc0, 0, 0, 0);
            acc1 = __builtin_amdgcn_mfma_f32_16x16x32_bf16(fa_l, bF[si][1][0], acc1, 0, 0, 0);
            acc1 = __builtin_amdgcn_mfma_f32_16x16x32_bf16(fa_h, bF[si][1][1], acc1, 0, 0, 0);
            acc1 = __builtin_amdgcn_mfma_f32_16x16x32_bf16(fa_h, bF[si][1][0], acc1, 0, 0, 0);
        }

        __syncthreads();   // all waves done reading fc1A before next quarter's writes
    }

    // ---- epilogue: cross-wave reduce (overlay on convA) + atomic FC1 partials
    float* red = (float*)convA;
#pragma unroll
    for (int r = 0; r < 4; ++r) {
        int node = (lane >> 4) * 4 + r;
        red[wv * 512 + node * 32 + nfr]      = acc0[r];
        red[wv * 512 + node * 32 + 16 + nfr] = acc1[r];
    }
    __syncthreads();
    {
        const int en = t >> 4, jp = t & 15;
        const int j0 = 2 * jp;
        float s0 = 0.f, s1 = 0.f;
#pragma unroll
        for (int wi = 0; wi < 4; ++wi) {
            s0 += red[wi * 512 + en * 32 + j0];
            s1 += red[wi * 512 + en * 32 + j0 + 1];
        }
        atomicAdd(&h_fc1[(size_t)(base + en) * 32 + j0],     s0);
        atomicAdd(&h_fc1[(size_t)(base + en) * 32 + j0 + 1], s1);
    }
}

// h_fc1 -> +b1, relu, FC2(+b2), relu -> h_cnn
__global__ __launch_bounds__(256) void fc1_finish(
    const float* __restrict__ h_fc1, const float* __restrict__ b1,
    const float* __restrict__ w2, const float* __restrict__ b2,
    float* __restrict__ h_out, int N)
{
    __shared__ float hr[8][32];
    const int t = threadIdx.x;
    const int nb = t >> 5, j = t & 31;
    const int n = blockIdx.x * 8 + nb;
    if (n < N) hr[nb][j] = fmaxf(h_fc1[(size_t)n * 32 + j] + b1[j], 0.f);
    __syncthreads();
    if (n >= N) return;
    float o = b2[j];
#pragma unroll
    for (int k = 0; k < 32; ++k) o = fmaf(hr[nb][k], w2[k * 32 + j], o);
    h_out[(size_t)n * 32 + j] = fmaxf(o, 0.f);
}

// --------------------------- CSR build (3-kernel scan) ---------------------
__global__ __launch_bounds__(256) void count_deg(
    const int* __restrict__ dst, int* __restrict__ cnt, int E)
{
    int e = blockIdx.x * 256 + threadIdx.x;
    if (e < E) atomicAdd(&cnt[dst[e]], 1);
}

__global__ __launch_bounds__(256) void scan_local(
    const int* __restrict__ cnt, int* __restrict__ excl, int* __restrict__ bsum, int N)
{
    __shared__ int s[256];
    int t = threadIdx.x, b = blockIdx.x, i = b * 256 + t;
    int v = (i < N) ? cnt[i] : 0;
    s[t] = v;
    __syncthreads();
#pragma unroll
    for (int off = 1; off < 256; off <<= 1) {
        int x = (t >= off) ? s[t - off] : 0;
        __syncthreads();
        s[t] += x;
        __syncthreads();
    }
    int incl = s[t];
    if (i < N) excl[i] = incl - v;
    if (t == 255) bsum[b] = incl;
}

__global__ __launch_bounds__(64) void scan_bsum(
    const int* __restrict__ bsum, int* __restrict__ bsumx, int* __restrict__ row_ptr,
    int nb, int N)
{
    int t = threadIdx.x;
    int v = (t < nb) ? bsum[t] : 0;
    int incl = v;
#pragma unroll
    for (int off = 1; off < 64; off <<= 1) {
        int x = __shfl_up(incl, off);
        if (t >= off) incl += x;
    }
    if (t < nb) bsumx[t] = incl - v;
    if (t == 63) row_ptr[N] = incl;   // == E
}

__global__ __launch_bounds__(256) void scan_add(
    const int* __restrict__ excl, const int* __restrict__ bsumx,
    int* __restrict__ row_ptr, int* __restrict__ cursor, int N)
{
    int i = blockIdx.x * 256 + threadIdx.x;
    if (i < N) {
        int rp = excl[i] + bsumx[i >> 8];
        row_ptr[i] = rp;
        cursor[i]  = rp;
    }
}

__global__ __launch_bounds__(256) void fill_csr(
    const int* __restrict__ src, const int* __restrict__ dst,
    int* __restrict__ cursor, int* __restrict__ csr, int E)
{
    int e = blockIdx.x * 256 + threadIdx.x;
    if (e >= E) return;
    int idx = atomicAdd(&cursor[dst[e]], 1);
    csr[idx] = src[e];
}

// --------------------------- fused SAGE-1 (+ z & self projections) ---------
// block = 4 nodes x 64 lanes. Phase A: 2-way edge-split gather -> shfl ->
// LDS. Phase B: h1 row = relu(h@s1_self + (agg/deg)@s1_neigh + b1) in LDS
// (no global h1). Phase C: lanes 0-9: z16 = h1@s2_neigh; lanes 16-25:
// self16 = s2_b + h1@s2_self.
__global__ __launch_bounds__(256) void sage1_fused(
    const float* __restrict__ h, const int* __restrict__ rp, const int* __restrict__ csr,
    const float* __restrict__ s1_self, const float* __restrict__ s1_neigh,
    const float* __restrict__ s1_b, const float* __restrict__ s2_neigh,
    const float* __restrict__ s2_self, const float* __restrict__ s2_b,
    float* __restrict__ z16, float* __restrict__ self16, int N)
{
    __shared__ float aggs[4][32];
    __shared__ float hl[4][64];
    const int t = threadIdx.x;
    const int nb = t >> 6, k = t & 63;
    const int n = blockIdx.x * 4 + nb;
    const int j = k & 31, half = k >> 5;

    int p0 = 0, p1 = 0;
    if (n < N) { p0 = rp[n]; p1 = rp[n + 1]; }
    float a = 0.f;
    for (int p = p0 + half; p < p1; p += 2)
        a += h[(size_t)csr[p] * 32 + j];
    a += __shfl_down(a, 32);
    if (half == 0) aggs[nb][j] = a;
    __syncthreads();

    float o = 0.f;
    if (n < N) {
        const int nu = __builtin_amdgcn_readfirstlane(n);
        float inv = 1.0f / fmaxf((float)(p1 - p0), 1.0f);
        o = s1_b[k];
#pragma unroll
        for (int jj = 0; jj < 32; ++jj) {
            o = fmaf(h[(size_t)nu * 32 + jj], s1_self[jj * 64 + k], o);
            o = fmaf(aggs[nb][jj] * inv, s1_neigh[jj * 64 + k], o);
        }
        o = fmaxf(o, 0.f);
    }
    hl[nb][k] = o;
    __syncthreads();

    if (n < N) {
        if (k < 10) {
            float z = 0.f;
#pragma unroll
            for (int jj = 0; jj < 64; ++jj) z = fmaf(hl[nb][jj], s2_neigh[jj * 10 + k], z);
            z16[(size_t)n * 16 + k] = z;
        } else if (k >= 16 && k < 26) {
            const int kk = k - 16;
            float s = s2_b[kk];
#pragma unroll
            for (int jj = 0; jj < 64; ++jj) s = fmaf(hl[nb][jj], s2_self[jj * 10 + kk], s);
            self16[(size_t)n * 16 + kk] = s;
        }
    }
}

// out = self16 + mean-gather(z16)
__global__ __launch_bounds__(256) void sage2_final_g(
    const float* __restrict__ z16, const float* __restrict__ self16,
    const int* __restrict__ rp, const int* __restrict__ csr,
    float* __restrict__ out, int N)
{
    int tid = blockIdx.x * 256 + threadIdx.x;
    int nn = tid >> 4, k = tid & 15;
    if (nn >= N || k >= 10) return;
    int p0 = rp[nn], p1 = rp[nn + 1];
    float a0 = 0.f, a1 = 0.f;
    int p = p0;
    for (; p + 2 <= p1; p += 2) {
        int s0 = csr[p], s1 = csr[p + 1];
        a0 += z16[(size_t)s0 * 16 + k];
        a1 += z16[(size_t)s1 * 16 + k];
    }
    if (p < p1) a0 += z16[(size_t)csr[p] * 16 + k];
    float inv = 1.0f / fmaxf((float)(p1 - p0), 1.0f);
    out[nn * 10 + k] = self16[(size_t)nn * 16 + k] + (a0 + a1) * inv;
}

extern "C" void kernel_launch(void* const* d_in, const int* in_sizes, int n_in,
                              void* d_out, int out_size, void* d_ws, size_t ws_size,
                              hipStream_t stream)
{
    const float* feat     = (const float*)d_in[0];
    const int*   src      = (const int*)d_in[1];
    const int*   dst      = (const int*)d_in[2];
    const float* conv_w   = (const float*)d_in[3];
    const float* conv_b   = (const float*)d_in[4];
    const float* w1       = (const float*)d_in[5];
    const float* b1       = (const float*)d_in[6];
    const float* w2       = (const float*)d_in[7];
    const float* b2       = (const float*)d_in[8];
    const float* s1_self  = (const float*)d_in[9];
    const float* s1_neigh = (const float*)d_in[10];
    const float* s1_b     = (const float*)d_in[11];
    const float* s2_self  = (const float*)d_in[12];
    const float* s2_neigh = (const float*)d_in[13];
    const float* s2_b     = (const float*)d_in[14];
    float* out = (float*)d_out;

    const int N = in_sizes[0] / 1280;  // 10000
    const int E = in_sizes[1];         // 320000
    const int NB_SCAN = (N + 255) / 256;  // 40

    // ws layout: [row_cnt N][h_fc1 32N]  <- contiguous, zeroed together
    char* wsb = (char*)d_ws;
    int*   row_cnt = (int*)wsb;                      wsb += (size_t)N * 4;
    float* h_fc1   = (float*)wsb;                    wsb += (size_t)N * 32 * 4;
    int*   excl    = (int*)wsb;                      wsb += (size_t)N * 4;
    int*   bsum    = (int*)wsb;                      wsb += 64 * 4;
    int*   bsumx   = (int*)wsb;                      wsb += 64 * 4;
    int*   row_ptr = (int*)wsb;                      wsb += (size_t)(N + 4) * 4;
    int*   cursor  = (int*)wsb;                      wsb += (size_t)N * 4;
    int*   csr     = (int*)wsb;                      wsb += (size_t)E * 4;
    float* h_cnn   = (float*)wsb;                    wsb += (size_t)N * 32 * 4;
    float* z16     = (float*)wsb;                    wsb += (size_t)N * 16 * 4;
    float* self16  = (float*)wsb;                    wsb += (size_t)N * 16 * 4;
    unsigned char* w1f = (unsigned char*)wsb;

    // zero row_cnt + h_fc1 (contiguous 33N words)
    zero_ws<<<(33 * N + 255) / 256, 256, 0, stream>>>((float*)row_cnt, 33 * N);

    // CSR build (3-kernel scan)
    count_deg<<<(E + 255) / 256, 256, 0, stream>>>(dst, row_cnt, E);
    scan_local<<<NB_SCAN, 256, 0, stream>>>(row_cnt, excl, bsum, N);
    scan_bsum<<<1, 64, 0, stream>>>(bsum, bsumx, row_ptr, NB_SCAN, N);
    scan_add<<<NB_SCAN, 256, 0, stream>>>(excl, bsumx, row_ptr, cursor, N);
    fill_csr<<<(E + 255) / 256, 256, 0, stream>>>(src, dst, cursor, csr, E);

    // CNN
    w1_prep_v3<<<320, 256, 0, stream>>>(w1, w1f);
    dim3 cg(N / 16, 8);
    cnn_fused_v15<<<cg, 256, 0, stream>>>(feat, conv_w, conv_b, w1f, h_fc1);
    fc1_finish<<<(N + 7) / 8, 256, 0, stream>>>(h_fc1, b1, w2, b2, h_cnn, N);

    // SAGE 1 (gather + transform + z & self projections fused; h1 stays in LDS)
    sage1_fused<<<(N + 3) / 4, 256, 0, stream>>>(
        h_cnn, row_ptr, csr, s1_self, s1_neigh, s1_b, s2_neigh, s2_self, s2_b,
        z16, self16, N);

    // SAGE 2: mean-gather of z + self
    sage2_final_g<<<(int)(((size_t)N * 16 + 255) / 256), 256, 0, stream>>>(
        z16, self16, row_ptr, csr, out, N);
}

// Round 16
// 202.017 us; speedup vs baseline: 1.0724x; 1.0724x over previous
//
#include <hip/hip_runtime.h>

// ---------------------------------------------------------------------------
// GCN pipeline: CNN(conv3x3+relu+pool2x2+FC1+FC2) -> SAGE(mean) -> SAGE(mean)
// Round 16: full revert to R14 (202.6 us proven: K-split x4, single fc1A,
// 2 barriers/quarter, R14 sage chain) + ONE lever: XCD-chunked bijective
// block swizzle (m204 form) so the 4 qq-siblings of each node-group share an
// XCD's L2 -> feat fetched once, 3x L2 hits. Numerics identical.
// ---------------------------------------------------------------------------

typedef __attribute__((ext_vector_type(8)))  short bf16x8;
typedef __attribute__((ext_vector_type(4)))  float f32x4;
typedef __attribute__((ext_vector_type(16))) float f32x16;

__device__ __forceinline__ unsigned short f2bf(float v) {
    union { float f; unsigned int u; } x; x.f = v;
    unsigned int r = x.u + 0x7FFFu + ((x.u >> 16) & 1u);  // RNE
    return (unsigned short)(r >> 16);
}
__device__ __forceinline__ float bf2f(unsigned short b) {
    union { float f; unsigned int u; } x; x.u = ((unsigned int)b) << 16;
    return x.f;
}
__device__ __forceinline__ unsigned cvtpk(float a, float b) {   // low16=bf(a), high16=bf(b)
    unsigned r;
    asm("v_cvt_pk_bf16_f32 %0, %1, %2" : "=v"(r) : "v"(a), "v"(b));
    return r;
}
__device__ __forceinline__ float lo2f(unsigned p) { union { unsigned u; float f; } x; x.u = p << 16; return x.f; }
__device__ __forceinline__ float hi2f(unsigned p) { union { unsigned u; float f; } x; x.u = p & 0xffff0000u; return x.f; }
__device__ __forceinline__ void split_pair(float a, float b, unsigned& hp, unsigned& lp) {
    hp = cvtpk(a, b);
    lp = cvtpk(a - lo2f(hp), b - hi2f(hp));
}

__global__ __launch_bounds__(256) void zero_ws(float* __restrict__ ws, int count) {
    int i = blockIdx.x * 256 + threadIdx.x;
    if (i < count) ws[i] = 0.0f;
}

// ---------------------------------------------------------------------------
// w1 prep (grid 320): fragment-ready bf16 hi/lo image per quarter (ph,qq).
// ---------------------------------------------------------------------------
__global__ __launch_bounds__(256) void w1_prep_v3(
    const float* __restrict__ w1, unsigned char* __restrict__ w1f)
{
    int gu = blockIdx.x * 256 + threadIdx.x;   // 0..81919
    const int quarter = gu >> 11;
    const int u = gu & 2047;
    const int ph = quarter >> 2, qq = quarter & 3;
    const int ks   = u >> 8;
    const int jh   = (u >> 7) & 1;
    const int part = (u >> 6) & 1;
    const int lane = u & 63;
    const int j    = jh * 16 + (lane & 15);
    const int c    = ks * 4 + (lane >> 4);
    const int k0   = c * 320 + ph * 32 + qq * 8;
    unsigned short v[8];
#pragma unroll
    for (int i = 0; i < 8; ++i) {
        float x = w1[(size_t)(k0 + i) * 32 + j];
        unsigned short h = f2bf(x);
        v[i] = part ? f2bf(x - bf2f(h)) : h;
    }
    *(uint4*)(w1f + (size_t)quarter * 32768 + (size_t)u * 16) = *(const uint4*)v;
}

// ---------------------------------------------------------------------------
// Fused CNN v16 (== R14 body): 16 nodes/block, 256 threads, 1D grid 2500
// with XCD-chunked bijective swizzle: hw block orig -> logical wgid so that
// logical work is contiguous per XCD (xcd = orig%8 round-robin assumption);
// wgid = 4*x + qq -> the 4 qq-siblings of node-group x share an XCD's L2.
// LDS: convA 18KB (swz byte ^= ((byte>>7)&3)<<4) + fc1A 16KB single buffer
// (swz byte ^= ((byte>>8)&7)<<4) = 34.8KB -> 4 blocks/CU. 2 barriers/quarter.
// ---------------------------------------------------------------------------
__global__ __launch_bounds__(256, 4) void cnn_fused_v16(
    const float* __restrict__ feat,
    const float* __restrict__ conv_w, const float* __restrict__ conv_b,
    const unsigned char* __restrict__ w1f,
    float* __restrict__ h_fc1)
{
    __shared__ __align__(16) unsigned char convA[18432];
    __shared__ __align__(16) unsigned char fc1A[16384];   // single buffer

    // ---- XCD-chunked bijective swizzle (nwg=2500, q=312, r=4; m204 form)
    const int orig = blockIdx.x;
    const int c8 = orig & 7;
    const int wgid = (c8 < 4 ? c8 * 313 : 4 * 313 + (c8 - 4) * 312) + (orig >> 3);
    const int xg = wgid >> 2;         // node-group 0..624
    const int qq = wgid & 3;          // column slice 0..3

    const int t = threadIdx.x;
    const int wv = t >> 6;            // 0..3
    const int lane = t & 63;
    const int base = xg * 16;

    const int nn  = lane >> 4;
    const int pwl = lane & 7;
    const int aa  = (lane >> 3) & 1;
    const float* featn = feat + (size_t)(base + wv * 4 + nn) * 1280;

    const int pw = qq * 8 + pwl;      // fixed pooled col
    const int c0 = 2 * pw - 1;        // fixed input col window c0..c0+3
    const bool cv0 = (c0 >= 0);
    const bool cv3 = (c0 + 3 < 64);

    const int cch = lane & 31;
    const int ckg = lane >> 5;
    const int rowr = lane & 31;
    unsigned rsw = (unsigned)(rowr << 4); rsw ^= ((rsw >> 7) & 3u) << 4;

    // conv weight fragments; k=9 carries the bias (A-side k9 input is 1.0)
    bf16x8 cbh, cbl;
    {
        union { unsigned short u[8]; bf16x8 v; } H, L;
#pragma unroll
        for (int i = 0; i < 8; ++i) {
            int k = ckg * 8 + i;
            float x = (k < 9) ? conv_w[cch * 9 + k] : (k == 9 ? conv_b[cch] : 0.0f);
            unsigned short h = f2bf(x);
            H.u[i] = h; L.u[i] = f2bf(x - bf2f(h));
        }
        cbh = H.v; cbl = L.v;
    }

    const int nfr = lane & 15;

    f32x4 acc0 = {0.f, 0.f, 0.f, 0.f};
    f32x4 acc1 = {0.f, 0.f, 0.f, 0.f};
    const f32x16 czero = {};    // hoisted zero C-operand

    float f0[4], f1[4], f2[4];
    auto load_row = [&](int r, float* o) {
        bool rv = (r >= 0) && (r < 20);
        const float* rp = featn + (rv ? r : 0) * 64;
        float2 m = *(const float2*)(rp + c0 + 1);    // c0+1 = 2pw: 8B-aligned, in-bounds
        float v0 = rp[cv0 ? c0 : 0];
        float v3 = rp[cv3 ? (c0 + 3) : 0];
        o[0] = (rv && cv0) ? v0 : 0.f;
        o[1] = rv ? m.x : 0.f;
        o[2] = rv ? m.y : 0.f;
        o[3] = (rv && cv3) ? v3 : 0.f;
    };

    load_row(aa - 1, f0);
    load_row(aa,     f1);
    load_row(aa + 1, f2);

#pragma unroll 1
    for (int ph = 0; ph < 10; ++ph) {
        const int quarter = ph * 4 + qq;
        unsigned char* fbuf = fc1A;

        // ---- (1) FC1 B-frags from global (L2); consumed in phase 4
        const unsigned char* wq = w1f + (size_t)quarter * 32768;
        bf16x8 bF[2][2][2];
#pragma unroll
        for (int si = 0; si < 2; ++si) {
            const int ks = wv + si * 4;
#pragma unroll
            for (int jh = 0; jh < 2; ++jh)
#pragma unroll
                for (int part = 0; part < 2; ++part)
                    bF[si][jh][part] = *(const bf16x8*)(
                        wq + (size_t)((((ks * 2 + jh) * 2 + part)) << 10) + lane * 16);
        }

        // ---- (2) split current rows -> convA + compact tap8
        {
            unsigned P[3][2], Q[3][2];
            split_pair(f0[0], f0[1], P[0][0], Q[0][0]);
            split_pair(f0[2], f0[3], P[0][1], Q[0][1]);
            split_pair(f1[0], f1[1], P[1][0], Q[1][0]);
            split_pair(f1[2], f1[3], P[1][1], Q[1][1]);
            split_pair(f2[0], f2[1], P[2][0], Q[2][0]);
            split_pair(f2[2], f2[3], P[2][1], Q[2][1]);

            const int r0 = pwl * 4 + aa * 2, r1 = r0 + 1;
            unsigned b0 = (unsigned)(r0 << 4); b0 ^= ((b0 >> 7) & 3u) << 4;
            unsigned b1 = (unsigned)(r1 << 4); b1 ^= ((b1 >> 7) & 3u) << 4;
            unsigned char* abw = convA + ((wv * 4 + nn) << 10);
            uint4 H0 = make_uint4(P[0][0],
                                  __builtin_amdgcn_perm(P[1][0], P[0][1], 0x05040100u),
                                  __builtin_amdgcn_perm(P[1][1], P[1][0], 0x05040302u),
                                  P[2][0]);
            uint4 H1 = make_uint4(__builtin_amdgcn_perm(P[0][1], P[0][0], 0x05040302u),
                                  __builtin_amdgcn_perm(P[1][0], P[0][1], 0x07060302u),
                                  P[1][1],
                                  __builtin_amdgcn_perm(P[2][1], P[2][0], 0x05040302u));
            uint4 L0 = make_uint4(Q[0][0],
                                  __builtin_amdgcn_perm(Q[1][0], Q[0][1], 0x05040100u),
                                  __builtin_amdgcn_perm(Q[1][1], Q[1][0], 0x05040302u),
                                  Q[2][0]);
            uint4 L1 = make_uint4(__builtin_amdgcn_perm(Q[0][1], Q[0][0], 0x05040302u),
                                  __builtin_amdgcn_perm(Q[1][0], Q[0][1], 0x07060302u),
                                  Q[1][1],
                                  __builtin_amdgcn_perm(Q[2][1], Q[2][0], 0x05040302u));
            *(uint4*)(abw + b0)       = H0;
            *(uint4*)(abw + b1)       = H1;
            *(uint4*)(abw + 512 + b0) = L0;
            *(uint4*)(abw + 512 + b1) = L1;
            unsigned wr0 = __builtin_amdgcn_perm(Q[2][1], P[2][1], 0x05040100u);
            unsigned wr1 = __builtin_amdgcn_perm(Q[2][1], P[2][1], 0x07060302u);
            *(uint2*)(convA + 16384 + (((wv * 4 + nn) * 32 + r0) << 2)) = make_uint2(wr0, wr1);
        }

        // ---- (2b) rotate window + prefetch next ph's two new rows
        if (ph < 9) {
#pragma unroll
            for (int j = 0; j < 4; ++j) f0[j] = f2[j];
            load_row(2 * ph + 2 + aa, f1);
            load_row(2 * ph + 3 + aa, f2);
        }

        // ---- (3) conv MFMA + in-lane pool + repack into fc1A
#pragma unroll
        for (int nn2 = 0; nn2 < 4; ++nn2) {
            bf16x8 a_h, a_l;
            if (ckg == 0) {
                const unsigned char* ab = convA + ((wv * 4 + nn2) << 10);
                a_h = *(const bf16x8*)(ab + rsw);
                a_l = *(const bf16x8*)(ab + 512 + rsw);
            } else {
                unsigned cw = *(const unsigned*)(convA + 16384 + (((wv * 4 + nn2) * 32 + rowr) << 2));
                // k=8: tap8 (hi/lo); k=9: constant 1.0 (bias tap; bf16(1.0)=0x3F80)
                a_h = (bf16x8){(short)(cw & 0xffffu), (short)0x3F80, 0, 0, 0, 0, 0, 0};
                a_l = (bf16x8){(short)(cw >> 16),     0,             0, 0, 0, 0, 0, 0};
            }
            f32x16 ca;
            ca = __builtin_amdgcn_mfma_f32_32x32x16_bf16(a_l, cbh, czero, 0, 0, 0);
            ca = __builtin_amdgcn_mfma_f32_32x32x16_bf16(a_h, cbl, ca, 0, 0, 0);
            ca = __builtin_amdgcn_mfma_f32_32x32x16_bf16(a_h, cbh, ca, 0, 0, 0);

            // bias already inside ca via k=9 tap; max(a+c,b+c)=max(a,b)+c
            float pv0 = fmaxf(fmaxf(fmaxf(ca[0],  ca[1]),  fmaxf(ca[2],  ca[3])),  0.f);
            float pv1 = fmaxf(fmaxf(fmaxf(ca[4],  ca[5]),  fmaxf(ca[6],  ca[7])),  0.f);
            float pv2 = fmaxf(fmaxf(fmaxf(ca[8],  ca[9]),  fmaxf(ca[10], ca[11])), 0.f);
            float pv3 = fmaxf(fmaxf(fmaxf(ca[12], ca[13]), fmaxf(ca[14], ca[15])), 0.f);

            unsigned ha, la, hb, lb;
            split_pair(pv0, pv1, ha, la);
            split_pair(pv2, pv3, hb, lb);
            unsigned pha = (unsigned)__shfl_xor((int)ha, 32);
            unsigned phb = (unsigned)__shfl_xor((int)hb, 32);
            unsigned pla = (unsigned)__shfl_xor((int)la, 32);
            unsigned plb = (unsigned)__shfl_xor((int)lb, 32);
            bool hih = (lane < 32);
            unsigned q0v = hih ? pha : la;
            unsigned q1v = hih ? ha  : pla;
            unsigned q2v = hih ? phb : lb;
            unsigned q3v = hih ? hb  : plb;
            unsigned w0  = __builtin_amdgcn_perm(q0v, q1v, 0x05040100u);
            unsigned w1v = __builtin_amdgcn_perm(q0v, q1v, 0x07060302u);
            unsigned w2v = __builtin_amdgcn_perm(q2v, q3v, 0x05040100u);
            unsigned w3v = __builtin_amdgcn_perm(q2v, q3v, 0x07060302u);
            const int nloc = wv * 4 + nn2;
            const int pS = hih ? 0 : 1;
            const int ksW = cch >> 2, kgW = cch & 3;
            unsigned byteW = (unsigned)((((pS * 8 + ksW) * 64) + kgW * 16 + nloc) << 4);
            byteW ^= ((byteW >> 8) & 7u) << 4;
            *(uint4*)(fbuf + byteW) = make_uint4(w0, w1v, w2v, w3v);
        }

        __syncthreads();   // fc1A writes visible to all waves

        // ---- (4) FC1 MFMA: wave wv handles ksteps {wv, wv+4}
#pragma unroll
        for (int si = 0; si < 2; ++si) {
            const int ks = wv + si * 4;
            unsigned bH = (unsigned)(((0 * 8 + ks) << 10) + lane * 16); bH ^= ((bH >> 8) & 7u) << 4;
            unsigned bL = (unsigned)(((1 * 8 + ks) << 10) + lane * 16); bL ^= ((bL >> 8) & 7u) << 4;
            bf16x8 fa_h = *(const bf16x8*)(fbuf + bH);
            bf16x8 fa_l = *(const bf16x8*)(fbuf + bL);
            acc0 = __builtin_amdgcn_mfma_f32_16x16x32_bf16(fa_l, bF[si][0][0], acc0, 0, 0, 0);
            acc0 = __builtin_amdgcn_mfma_f32_16x16x32_bf16(fa_h, bF[si][0][1], acc0, 0, 0, 0);
            acc0 = __builtin_amdgcn_mfma_f32_16x16x32_bf16(fa_h, bF[si][0][0], acc0, 0, 0, 0);
            acc1 = __builtin_amdgcn_mfma_f32_16x16x32_bf16(fa_l, bF[si][1][0], acc1, 0, 0, 0);
            acc1 = __builtin_amdgcn_mfma_f32_16x16x32_bf16(fa_h, bF[si][1][1], acc1, 0, 0, 0);
            acc1 = __builtin_amdgcn_mfma_f32_16x16x32_bf16(fa_h, bF[si][1][0], acc1, 0, 0, 0);
        }

        __syncthreads();   // all waves done reading fc1A before next quarter's writes
    }

    // ---- epilogue: cross-wave reduce (overlay on convA) + atomic FC1 partials
    float* red = (float*)convA;
#pragma unroll
    for (int r = 0; r < 4; ++r) {
        int node = (lane >> 4) * 4 + r;
        red[wv * 512 + node * 32 + nfr]      = acc0[r];
        red[wv * 512 + node * 32 + 16 + nfr] = acc1[r];
    }
    __syncthreads();
    {
        const int en = t >> 4, jp = t & 15;
        const int j0 = 2 * jp;
        float s0 = 0.f, s1 = 0.f;
#pragma unroll
        for (int wi = 0; wi < 4; ++wi) {
            s0 += red[wi * 512 + en * 32 + j0];
            s1 += red[wi * 512 + en * 32 + j0 + 1];
        }
        atomicAdd(&h_fc1[(size_t)(base + en) * 32 + j0],     s0);
        atomicAdd(&h_fc1[(size_t)(base + en) * 32 + j0 + 1], s1);
    }
}

// h_fc1 -> +b1, relu, FC2(+b2), relu -> h_cnn
__global__ __launch_bounds__(256) void fc1_finish(
    const float* __restrict__ h_fc1, const float* __restrict__ b1,
    const float* __restrict__ w2, const float* __restrict__ b2,
    float* __restrict__ h_out, int N)
{
    __shared__ float hr[8][32];
    const int t = threadIdx.x;
    const int nb = t >> 5, j = t & 31;
    const int n = blockIdx.x * 8 + nb;
    if (n < N) hr[nb][j] = fmaxf(h_fc1[(size_t)n * 32 + j] + b1[j], 0.f);
    __syncthreads();
    if (n >= N) return;
    float o = b2[j];
#pragma unroll
    for (int k = 0; k < 32; ++k) o = fmaf(hr[nb][k], w2[k * 32 + j], o);
    h_out[(size_t)n * 32 + j] = fmaxf(o, 0.f);
}

// --------------------------- CSR build (3-kernel scan) ---------------------
__global__ __launch_bounds__(256) void count_deg(
    const int* __restrict__ dst, int* __restrict__ cnt, int E)
{
    int e = blockIdx.x * 256 + threadIdx.x;
    if (e < E) atomicAdd(&cnt[dst[e]], 1);
}

__global__ __launch_bounds__(256) void scan_local(
    const int* __restrict__ cnt, int* __restrict__ excl, int* __restrict__ bsum, int N)
{
    __shared__ int s[256];
    int t = threadIdx.x, b = blockIdx.x, i = b * 256 + t;
    int v = (i < N) ? cnt[i] : 0;
    s[t] = v;
    __syncthreads();
#pragma unroll
    for (int off = 1; off < 256; off <<= 1) {
        int x = (t >= off) ? s[t - off] : 0;
        __syncthreads();
        s[t] += x;
        __syncthreads();
    }
    int incl = s[t];
    if (i < N) excl[i] = incl - v;
    if (t == 255) bsum[b] = incl;
}

__global__ __launch_bounds__(64) void scan_bsum(
    const int* __restrict__ bsum, int* __restrict__ bsumx, int* __restrict__ row_ptr,
    int nb, int N)
{
    int t = threadIdx.x;
    int v = (t < nb) ? bsum[t] : 0;
    int incl = v;
#pragma unroll
    for (int off = 1; off < 64; off <<= 1) {
        int x = __shfl_up(incl, off);
        if (t >= off) incl += x;
    }
    if (t < nb) bsumx[t] = incl - v;
    if (t == 63) row_ptr[N] = incl;   // == E
}

__global__ __launch_bounds__(256) void scan_add(
    const int* __restrict__ excl, const int* __restrict__ bsumx,
    int* __restrict__ row_ptr, int* __restrict__ cursor, int N)
{
    int i = blockIdx.x * 256 + threadIdx.x;
    if (i < N) {
        int rp = excl[i] + bsumx[i >> 8];
        row_ptr[i] = rp;
        cursor[i]  = rp;
    }
}

__global__ __launch_bounds__(256) void fill_csr(
    const int* __restrict__ src, const int* __restrict__ dst,
    int* __restrict__ cursor, int* __restrict__ csr, int E)
{
    int e = blockIdx.x * 256 + threadIdx.x;
    if (e >= E) return;
    int idx = atomicAdd(&cursor[dst[e]], 1);
    csr[idx] = src[e];
}

// --------------------------- fused SAGE-1 (+ z projection) -----------------
__global__ __launch_bounds__(256) void sage1_fused(
    const float* __restrict__ h, const int* __restrict__ rp, const int* __restrict__ csr,
    const float* __restrict__ s1_self, const float* __restrict__ s1_neigh,
    const float* __restrict__ s1_b, const float* __restrict__ s2_neigh,
    float* __restrict__ h1, float* __restrict__ z16, int N)
{
    __shared__ float aggs[4][32];
    __shared__ float hl[4][64];
    const int t = threadIdx.x;
    const int nb = t >> 6, k = t & 63;
    const int n = blockIdx.x * 4 + nb;
    const int j = k & 31, half = k >> 5;

    int p0 = 0, p1 = 0;
    if (n < N) { p0 = rp[n]; p1 = rp[n + 1]; }
    float a = 0.f;
    for (int p = p0 + half; p < p1; p += 2)
        a += h[(size_t)csr[p] * 32 + j];
    a += __shfl_down(a, 32);
    if (half == 0) aggs[nb][j] = a;
    __syncthreads();

    float o = 0.f;
    if (n < N) {
        const int nu = __builtin_amdgcn_readfirstlane(n);
        float inv = 1.0f / fmaxf((float)(p1 - p0), 1.0f);
        o = s1_b[k];
#pragma unroll
        for (int jj = 0; jj < 32; ++jj) {
            o = fmaf(h[(size_t)nu * 32 + jj], s1_self[jj * 64 + k], o);
            o = fmaf(aggs[nb][jj] * inv, s1_neigh[jj * 64 + k], o);
        }
        o = fmaxf(o, 0.f);
        h1[(size_t)n * 64 + k] = o;
    }
    hl[nb][k] = o;
    __syncthreads();

    if (n < N && k < 16) {
        float z = 0.f;
        if (k < 10) {
#pragma unroll
            for (int jj = 0; jj < 64; ++jj) z = fmaf(hl[nb][jj], s2_neigh[jj * 10 + k], z);
        }
        z16[(size_t)n * 16 + k] = z;
    }
}

__global__ __launch_bounds__(256) void sage2_final_g(
    const float* __restrict__ h1, const float* __restrict__ z16,
    const int* __restrict__ rp, const int* __restrict__ csr,
    const float* __restrict__ s2_self, const float* __restrict__ s2_b,
    float* __restrict__ out, int N)
{
    int tid = blockIdx.x * 256 + threadIdx.x;
    int nn = tid >> 4, k = tid & 15;
    if (nn >= N || k >= 10) return;
    int p0 = rp[nn], p1 = rp[nn + 1];
    float a0 = 0.f, a1 = 0.f;
    int p = p0;
    for (; p + 2 <= p1; p += 2) {
        int s0 = csr[p], s1 = csr[p + 1];
        a0 += z16[(size_t)s0 * 16 + k];
        a1 += z16[(size_t)s1 * 16 + k];
    }
    if (p < p1) a0 += z16[(size_t)csr[p] * 16 + k];
    float inv = 1.0f / fmaxf((float)(p1 - p0), 1.0f);
    float o = s2_b[k] + (a0 + a1) * inv;
#pragma unroll
    for (int j = 0; j < 64; ++j) o = fmaf(h1[nn * 64 + j], s2_self[j * 10 + k], o);
    out[nn * 10 + k] = o;
}

extern "C" void kernel_launch(void* const* d_in, const int* in_sizes, int n_in,
                              void* d_out, int out_size, void* d_ws, size_t ws_size,
                              hipStream_t stream)
{
    const float* feat     = (const float*)d_in[0];
    const int*   src      = (const int*)d_in[1];
    const int*   dst      = (const int*)d_in[2];
    const float* conv_w   = (const float*)d_in[3];
    const float* conv_b   = (const float*)d_in[4];
    const float* w1       = (const float*)d_in[5];
    const float* b1       = (const float*)d_in[6];
    const float* w2       = (const float*)d_in[7];
    const float* b2       = (const float*)d_in[8];
    const float* s1_self  = (const float*)d_in[9];
    const float* s1_neigh = (const float*)d_in[10];
    const float* s1_b     = (const float*)d_in[11];
    const float* s2_self  = (const float*)d_in[12];
    const float* s2_neigh = (const float*)d_in[13];
    const float* s2_b     = (const float*)d_in[14];
    float* out = (float*)d_out;

    const int N = in_sizes[0] / 1280;  // 10000
    const int E = in_sizes[1];         // 320000
    const int NB_SCAN = (N + 255) / 256;  // 40

    // ws layout: [row_cnt N][h_fc1 32N]  <- contiguous, zeroed together
    char* wsb = (char*)d_ws;
    int*   row_cnt = (int*)wsb;                      wsb += (size_t)N * 4;
    float* h_fc1   = (float*)wsb;                    wsb += (size_t)N * 32 * 4;
    int*   excl    = (int*)wsb;                      wsb += (size_t)N * 4;
    int*   bsum    = (int*)wsb;                      wsb += 64 * 4;
    int*   bsumx   = (int*)wsb;                      wsb += 64 * 4;
    int*   row_ptr = (int*)wsb;                      wsb += (size_t)(N + 4) * 4;
    int*   cursor  = (int*)wsb;                      wsb += (size_t)N * 4;
    int*   csr     = (int*)wsb;                      wsb += (size_t)E * 4;
    float* h_cnn   = (float*)wsb;                    wsb += (size_t)N * 32 * 4;
    float* h1      = (float*)wsb;                    wsb += (size_t)N * 64 * 4;
    float* z16     = (float*)wsb;                    wsb += (size_t)N * 16 * 4;
    unsigned char* w1f = (unsigned char*)wsb;

    // zero row_cnt + h_fc1 (contiguous 33N words)
    zero_ws<<<(33 * N + 255) / 256, 256, 0, stream>>>((float*)row_cnt, 33 * N);

    // CSR build (3-kernel scan)
    count_deg<<<(E + 255) / 256, 256, 0, stream>>>(dst, row_cnt, E);
    scan_local<<<NB_SCAN, 256, 0, stream>>>(row_cnt, excl, bsum, N);
    scan_bsum<<<1, 64, 0, stream>>>(bsum, bsumx, row_ptr, NB_SCAN, N);
    scan_add<<<NB_SCAN, 256, 0, stream>>>(excl, bsumx, row_ptr, cursor, N);
    fill_csr<<<(E + 255) / 256, 256, 0, stream>>>(src, dst, cursor, csr, E);

    // CNN (1D grid 2500, XCD-chunked swizzle inside the kernel)
    w1_prep_v3<<<320, 256, 0, stream>>>(w1, w1f);
    cnn_fused_v16<<<(N / 16) * 4, 256, 0, stream>>>(feat, conv_w, conv_b, w1f, h_fc1);
    fc1_finish<<<(N + 7) / 8, 256, 0, stream>>>(h_fc1, b1, w2, b2, h_cnn, N);

    // SAGE 1 (gather + transform + z projection fused)
    sage1_fused<<<(N + 3) / 4, 256, 0, stream>>>(
        h_cnn, row_ptr, csr, s1_self, s1_neigh, s1_b, s2_neigh, h1, z16, N);

    // SAGE 2
    sage2_final_g<<<(int)(((size_t)N * 16 + 255) / 256), 256, 0, stream>>>(
        h1, z16, row_ptr, csr, s2_self, s2_b, out, N);
}

// Round 17
// 193.982 us; speedup vs baseline: 1.1168x; 1.0414x over previous
//
#include <hip/hip_runtime.h>

// ---------------------------------------------------------------------------
// GCN pipeline: CNN(conv3x3+relu+pool2x2+FC1+FC2) -> SAGE(mean) -> SAGE(mean)
// Round 17: R16 + phase-3 repack without cross-lane ops: the within-unit
// k-order of fc1A/w1f is permuted (pos i <-> pwl 2i / 2(i-4)+1) so each
// lane's 4 pooled bf16 are contiguous -> two ds_write_b64 per nn2 replace
// 4 shfl + 4 cndmask + 4 perm + 1 b128. w1_prep stores the same order.
// Numerics identical (absmax ~2.4e-4).
// ---------------------------------------------------------------------------

typedef __attribute__((ext_vector_type(8)))  short bf16x8;
typedef __attribute__((ext_vector_type(4)))  float f32x4;
typedef __attribute__((ext_vector_type(16))) float f32x16;

__device__ __forceinline__ unsigned short f2bf(float v) {
    union { float f; unsigned int u; } x; x.f = v;
    unsigned int r = x.u + 0x7FFFu + ((x.u >> 16) & 1u);  // RNE
    return (unsigned short)(r >> 16);
}
__device__ __forceinline__ float bf2f(unsigned short b) {
    union { float f; unsigned int u; } x; x.u = ((unsigned int)b) << 16;
    return x.f;
}
__device__ __forceinline__ unsigned cvtpk(float a, float b) {   // low16=bf(a), high16=bf(b)
    unsigned r;
    asm("v_cvt_pk_bf16_f32 %0, %1, %2" : "=v"(r) : "v"(a), "v"(b));
    return r;
}
__device__ __forceinline__ float lo2f(unsigned p) { union { unsigned u; float f; } x; x.u = p << 16; return x.f; }
__device__ __forceinline__ float hi2f(unsigned p) { union { unsigned u; float f; } x; x.u = p & 0xffff0000u; return x.f; }
__device__ __forceinline__ void split_pair(float a, float b, unsigned& hp, unsigned& lp) {
    hp = cvtpk(a, b);
    lp = cvtpk(a - lo2f(hp), b - hi2f(hp));
}

__global__ __launch_bounds__(256) void zero_ws(float* __restrict__ ws, int count) {
    int i = blockIdx.x * 256 + threadIdx.x;
    if (i < count) ws[i] = 0.0f;
}

// ---------------------------------------------------------------------------
// w1 prep (grid 320): fragment-ready bf16 hi/lo image per quarter (ph,qq).
// Within-unit position i maps to pwl: i<4 -> 2i, else 2(i-4)+1 (matches the
// direct-b64 A-side writes; A/B pair positionally inside the MFMA).
// ---------------------------------------------------------------------------
__global__ __launch_bounds__(256) void w1_prep_v4(
    const float* __restrict__ w1, unsigned char* __restrict__ w1f)
{
    int gu = blockIdx.x * 256 + threadIdx.x;   // 0..81919
    const int quarter = gu >> 11;
    const int u = gu & 2047;
    const int ph = quarter >> 2, qq = quarter & 3;
    const int ks   = u >> 8;
    const int jh   = (u >> 7) & 1;
    const int part = (u >> 6) & 1;
    const int lane = u & 63;
    const int j    = jh * 16 + (lane & 15);
    const int c    = ks * 4 + (lane >> 4);
    const int k0   = c * 320 + ph * 32 + qq * 8;
    unsigned short v[8];
#pragma unroll
    for (int i = 0; i < 8; ++i) {
        const int pwl_i = (i < 4) ? (2 * i) : (2 * (i - 4) + 1);
        float x = w1[(size_t)(k0 + pwl_i) * 32 + j];
        unsigned short h = f2bf(x);
        v[i] = part ? f2bf(x - bf2f(h)) : h;
    }
    *(uint4*)(w1f + (size_t)quarter * 32768 + (size_t)u * 16) = *(const uint4*)v;
}

// ---------------------------------------------------------------------------
// Fused CNN v17: 16 nodes/block, 256 threads, 1D grid 2500, XCD-chunked
// bijective swizzle. Single fc1A, 2 barriers/quarter, bias as K=9 tap,
// direct-b64 pool repack (no shfl/perm). LDS 34.8KB -> 4 blocks/CU.
// ---------------------------------------------------------------------------
__global__ __launch_bounds__(256, 4) void cnn_fused_v17(
    const float* __restrict__ feat,
    const float* __restrict__ conv_w, const float* __restrict__ conv_b,
    const unsigned char* __restrict__ w1f,
    float* __restrict__ h_fc1)
{
    __shared__ __align__(16) unsigned char convA[18432];
    __shared__ __align__(16) unsigned char fc1A[16384];   // single buffer

    // ---- XCD-chunked bijective swizzle (nwg=2500, q=312, r=4; m204 form)
    const int orig = blockIdx.x;
    const int c8 = orig & 7;
    const int wgid = (c8 < 4 ? c8 * 313 : 4 * 313 + (c8 - 4) * 312) + (orig >> 3);
    const int xg = wgid >> 2;         // node-group 0..624
    const int qq = wgid & 3;          // column slice 0..3

    const int t = threadIdx.x;
    const int wv = t >> 6;            // 0..3
    const int lane = t & 63;
    const int base = xg * 16;

    const int nn  = lane >> 4;
    const int pwl = lane & 7;
    const int aa  = (lane >> 3) & 1;
    const float* featn = feat + (size_t)(base + wv * 4 + nn) * 1280;

    const int pw = qq * 8 + pwl;      // fixed pooled col
    const int c0 = 2 * pw - 1;        // fixed input col window c0..c0+3
    const bool cv0 = (c0 >= 0);
    const bool cv3 = (c0 + 3 < 64);

    const int cch = lane & 31;
    const int ckg = lane >> 5;        // conv K-group AND output half h
    const int rowr = lane & 31;
    unsigned rsw = (unsigned)(rowr << 4); rsw ^= ((rsw >> 7) & 3u) << 4;

    // conv weight fragments; k=9 carries the bias (A-side k9 input is 1.0)
    bf16x8 cbh, cbl;
    {
        union { unsigned short u[8]; bf16x8 v; } H, L;
#pragma unroll
        for (int i = 0; i < 8; ++i) {
            int k = ckg * 8 + i;
            float x = (k < 9) ? conv_w[cch * 9 + k] : (k == 9 ? conv_b[cch] : 0.0f);
            unsigned short h = f2bf(x);
            H.u[i] = h; L.u[i] = f2bf(x - bf2f(h));
        }
        cbh = H.v; cbl = L.v;
    }

    const int nfr = lane & 15;
    const unsigned hoff = (unsigned)(ckg << 3);   // h*8: within-unit byte offset

    f32x4 acc0 = {0.f, 0.f, 0.f, 0.f};
    f32x4 acc1 = {0.f, 0.f, 0.f, 0.f};
    const f32x16 czero = {};    // hoisted zero C-operand

    float f0[4], f1[4], f2[4];
    auto load_row = [&](int r, float* o) {
        bool rv = (r >= 0) && (r < 20);
        const float* rp = featn + (rv ? r : 0) * 64;
        float2 m = *(const float2*)(rp + c0 + 1);    // c0+1 = 2pw: 8B-aligned, in-bounds
        float v0 = rp[cv0 ? c0 : 0];
        float v3 = rp[cv3 ? (c0 + 3) : 0];
        o[0] = (rv && cv0) ? v0 : 0.f;
        o[1] = rv ? m.x : 0.f;
        o[2] = rv ? m.y : 0.f;
        o[3] = (rv && cv3) ? v3 : 0.f;
    };

    load_row(aa - 1, f0);
    load_row(aa,     f1);
    load_row(aa + 1, f2);

#pragma unroll 1
    for (int ph = 0; ph < 10; ++ph) {
        const int quarter = ph * 4 + qq;
        unsigned char* fbuf = fc1A;

        // ---- (1) FC1 B-frags from global (L2); consumed in phase 4
        const unsigned char* wq = w1f + (size_t)quarter * 32768;
        bf16x8 bF[2][2][2];
#pragma unroll
        for (int si = 0; si < 2; ++si) {
            const int ks = wv + si * 4;
#pragma unroll
            for (int jh = 0; jh < 2; ++jh)
#pragma unroll
                for (int part = 0; part < 2; ++part)
                    bF[si][jh][part] = *(const bf16x8*)(
                        wq + (size_t)((((ks * 2 + jh) * 2 + part)) << 10) + lane * 16);
        }

        // ---- (2) split current rows -> convA + compact tap8
        {
            unsigned P[3][2], Q[3][2];
            split_pair(f0[0], f0[1], P[0][0], Q[0][0]);
            split_pair(f0[2], f0[3], P[0][1], Q[0][1]);
            split_pair(f1[0], f1[1], P[1][0], Q[1][0]);
            split_pair(f1[2], f1[3], P[1][1], Q[1][1]);
            split_pair(f2[0], f2[1], P[2][0], Q[2][0]);
            split_pair(f2[2], f2[3], P[2][1], Q[2][1]);

            const int r0 = pwl * 4 + aa * 2, r1 = r0 + 1;
            unsigned b0 = (unsigned)(r0 << 4); b0 ^= ((b0 >> 7) & 3u) << 4;
            unsigned b1 = (unsigned)(r1 << 4); b1 ^= ((b1 >> 7) & 3u) << 4;
            unsigned char* abw = convA + ((wv * 4 + nn) << 10);
            uint4 H0 = make_uint4(P[0][0],
                                  __builtin_amdgcn_perm(P[1][0], P[0][1], 0x05040100u),
                                  __builtin_amdgcn_perm(P[1][1], P[1][0], 0x05040302u),
                                  P[2][0]);
            uint4 H1 = make_uint4(__builtin_amdgcn_perm(P[0][1], P[0][0], 0x05040302u),
                                  __builtin_amdgcn_perm(P[1][0], P[0][1], 0x07060302u),
                                  P[1][1],
                                  __builtin_amdgcn_perm(P[2][1], P[2][0], 0x05040302u));
            uint4 L0 = make_uint4(Q[0][0],
                                  __builtin_amdgcn_perm(Q[1][0], Q[0][1], 0x05040100u),
                                  __builtin_amdgcn_perm(Q[1][1], Q[1][0], 0x05040302u),
                                  Q[2][0]);
            uint4 L1 = make_uint4(__builtin_amdgcn_perm(Q[0][1], Q[0][0], 0x05040302u),
                                  __builtin_amdgcn_perm(Q[1][0], Q[0][1], 0x07060302u),
                                  Q[1][1],
                                  __builtin_amdgcn_perm(Q[2][1], Q[2][0], 0x05040302u));
            *(uint4*)(abw + b0)       = H0;
            *(uint4*)(abw + b1)       = H1;
            *(uint4*)(abw + 512 + b0) = L0;
            *(uint4*)(abw + 512 + b1) = L1;
            unsigned wr0 = __builtin_amdgcn_perm(Q[2][1], P[2][1], 0x05040100u);
            unsigned wr1 = __builtin_amdgcn_perm(Q[2][1], P[2][1], 0x07060302u);
            *(uint2*)(convA + 16384 + (((wv * 4 + nn) * 32 + r0) << 2)) = make_uint2(wr0, wr1);
        }

        // ---- (2b) rotate window + prefetch next ph's two new rows
        if (ph < 9) {
#pragma unroll
            for (int j = 0; j < 4; ++j) f0[j] = f2[j];
            load_row(2 * ph + 2 + aa, f1);
            load_row(2 * ph + 3 + aa, f2);
        }

        // ---- (3) conv MFMA + in-lane pool + direct-b64 repack into fc1A
#pragma unroll
        for (int nn2 = 0; nn2 < 4; ++nn2) {
            bf16x8 a_h, a_l;
            if (ckg == 0) {
                const unsigned char* ab = convA + ((wv * 4 + nn2) << 10);
                a_h = *(const bf16x8*)(ab + rsw);
                a_l = *(const bf16x8*)(ab + 512 + rsw);
            } else {
                unsigned cw = *(const unsigned*)(convA + 16384 + (((wv * 4 + nn2) * 32 + rowr) << 2));
                // k=8: tap8 (hi/lo); k=9: constant 1.0 (bias tap; bf16(1.0)=0x3F80)
                a_h = (bf16x8){(short)(cw & 0xffffu), (short)0x3F80, 0, 0, 0, 0, 0, 0};
                a_l = (bf16x8){(short)(cw >> 16),     0,             0, 0, 0, 0, 0, 0};
            }
            f32x16 ca;
            ca = __builtin_amdgcn_mfma_f32_32x32x16_bf16(a_l, cbh, czero, 0, 0, 0);
            ca = __builtin_amdgcn_mfma_f32_32x32x16_bf16(a_h, cbl, ca, 0, 0, 0);
            ca = __builtin_amdgcn_mfma_f32_32x32x16_bf16(a_h, cbh, ca, 0, 0, 0);

            // bias already inside ca via k=9 tap; max(a+c,b+c)=max(a,b)+c
            // lane (cch, h=ckg) holds pooled values for pwl = 2i + h, i=0..3
            float pv0 = fmaxf(fmaxf(fmaxf(ca[0],  ca[1]),  fmaxf(ca[2],  ca[3])),  0.f);
            float pv1 = fmaxf(fmaxf(fmaxf(ca[4],  ca[5]),  fmaxf(ca[6],  ca[7])),  0.f);
            float pv2 = fmaxf(fmaxf(fmaxf(ca[8],  ca[9]),  fmaxf(ca[10], ca[11])), 0.f);
            float pv3 = fmaxf(fmaxf(fmaxf(ca[12], ca[13]), fmaxf(ca[14], ca[15])), 0.f);

            unsigned ha, la, hb, lb;
            split_pair(pv0, pv1, ha, la);
            split_pair(pv2, pv3, hb, lb);

            const int nloc = wv * 4 + nn2;
            const int ksW = cch >> 2, kgW = cch & 3;
            unsigned bh = (unsigned)((((0 * 8 + ksW) * 64) + kgW * 16 + nloc) << 4);
            bh ^= ((bh >> 8) & 7u) << 4;
            unsigned bl = (unsigned)((((1 * 8 + ksW) * 64) + kgW * 16 + nloc) << 4);
            bl ^= ((bl >> 8) & 7u) << 4;
            *(uint2*)(fbuf + bh + hoff) = make_uint2(ha, hb);
            *(uint2*)(fbuf + bl + hoff) = make_uint2(la, lb);
        }

        __syncthreads();   // fc1A writes visible to all waves

        // ---- (4) FC1 MFMA: wave wv handles ksteps {wv, wv+4}
#pragma unroll
        for (int si = 0; si < 2; ++si) {
            const int ks = wv + si * 4;
            unsigned bH = (unsigned)(((0 * 8 + ks) << 10) + lane * 16); bH ^= ((bH >> 8) & 7u) << 4;
            unsigned bL = (unsigned)(((1 * 8 + ks) << 10) + lane * 16); bL ^= ((bL >> 8) & 7u) << 4;
            bf16x8 fa_h = *(const bf16x8*)(fbuf + bH);
            bf16x8 fa_l = *(const bf16x8*)(fbuf + bL);
            acc0 = __builtin_amdgcn_mfma_f32_16x16x32_bf16(fa_l, bF[si][0][0], acc0, 0, 0, 0);
            acc0 = __builtin_amdgcn_mfma_f32_16x16x32_bf16(fa_h, bF[si][0][1], acc0, 0, 0, 0);
            acc0 = __builtin_amdgcn_mfma_f32_16x16x32_bf16(fa_h, bF[si][0][0], acc0, 0, 0, 0);
            acc1 = __builtin_amdgcn_mfma_f32_16x16x32_bf16(fa_l, bF[si][1][0], acc1, 0, 0, 0);
            acc1 = __builtin_amdgcn_mfma_f32_16x16x32_bf16(fa_h, bF[si][1][1], acc1, 0, 0, 0);
            acc1 = __builtin_amdgcn_mfma_f32_16x16x32_bf16(fa_h, bF[si][1][0], acc1, 0, 0, 0);
        }

        __syncthreads();   // all waves done reading fc1A before next quarter's writes
    }

    // ---- epilogue: cross-wave reduce (overlay on convA) + atomic FC1 partials
    float* red = (float*)convA;
#pragma unroll
    for (int r = 0; r < 4; ++r) {
        int node = (lane >> 4) * 4 + r;
        red[wv * 512 + node * 32 + nfr]      = acc0[r];
        red[wv * 512 + node * 32 + 16 + nfr] = acc1[r];
    }
    __syncthreads();
    {
        const int en = t >> 4, jp = t & 15;
        const int j0 = 2 * jp;
        float s0 = 0.f, s1 = 0.f;
#pragma unroll
        for (int wi = 0; wi < 4; ++wi) {
            s0 += red[wi * 512 + en * 32 + j0];
            s1 += red[wi * 512 + en * 32 + j0 + 1];
        }
        atomicAdd(&h_fc1[(size_t)(base + en) * 32 + j0],     s0);
        atomicAdd(&h_fc1[(size_t)(base + en) * 32 + j0 + 1], s1);
    }
}

// h_fc1 -> +b1, relu, FC2(+b2), relu -> h_cnn
__global__ __launch_bounds__(256) void fc1_finish(
    const float* __restrict__ h_fc1, const float* __restrict__ b1,
    const float* __restrict__ w2, const float* __restrict__ b2,
    float* __restrict__ h_out, int N)
{
    __shared__ float hr[8][32];
    const int t = threadIdx.x;
    const int nb = t >> 5, j = t & 31;
    const int n = blockIdx.x * 8 + nb;
    if (n < N) hr[nb][j] = fmaxf(h_fc1[(size_t)n * 32 + j] + b1[j], 0.f);
    __syncthreads();
    if (n >= N) return;
    float o = b2[j];
#pragma unroll
    for (int k = 0; k < 32; ++k) o = fmaf(hr[nb][k], w2[k * 32 + j], o);
    h_out[(size_t)n * 32 + j] = fmaxf(o, 0.f);
}

// --------------------------- CSR build (3-kernel scan) ---------------------
__global__ __launch_bounds__(256) void count_deg(
    const int* __restrict__ dst, int* __restrict__ cnt, int E)
{
    int e = blockIdx.x * 256 + threadIdx.x;
    if (e < E) atomicAdd(&cnt[dst[e]], 1);
}

__global__ __launch_bounds__(256) void scan_local(
    const int* __restrict__ cnt, int* __restrict__ excl, int* __restrict__ bsum, int N)
{
    __shared__ int s[256];
    int t = threadIdx.x, b = blockIdx.x, i = b * 256 + t;
    int v = (i < N) ? cnt[i] : 0;
    s[t] = v;
    __syncthreads();
#pragma unroll
    for (int off = 1; off < 256; off <<= 1) {
        int x = (t >= off) ? s[t - off] : 0;
        __syncthreads();
        s[t] += x;
        __syncthreads();
    }
    int incl = s[t];
    if (i < N) excl[i] = incl - v;
    if (t == 255) bsum[b] = incl;
}

__global__ __launch_bounds__(64) void scan_bsum(
    const int* __restrict__ bsum, int* __restrict__ bsumx, int* __restrict__ row_ptr,
    int nb, int N)
{
    int t = threadIdx.x;
    int v = (t < nb) ? bsum[t] : 0;
    int incl = v;
#pragma unroll
    for (int off = 1; off < 64; off <<= 1) {
        int x = __shfl_up(incl, off);
        if (t >= off) incl += x;
    }
    if (t < nb) bsumx[t] = incl - v;
    if (t == 63) row_ptr[N] = incl;   // == E
}

__global__ __launch_bounds__(256) void scan_add(
    const int* __restrict__ excl, const int* __restrict__ bsumx,
    int* __restrict__ row_ptr, int* __restrict__ cursor, int N)
{
    int i = blockIdx.x * 256 + threadIdx.x;
    if (i < N) {
        int rp = excl[i] + bsumx[i >> 8];
        row_ptr[i] = rp;
        cursor[i]  = rp;
    }
}

__global__ __launch_bounds__(256) void fill_csr(
    const int* __restrict__ src, const int* __restrict__ dst,
    int* __restrict__ cursor, int* __restrict__ csr, int E)
{
    int e = blockIdx.x * 256 + threadIdx.x;
    if (e >= E) return;
    int idx = atomicAdd(&cursor[dst[e]], 1);
    csr[idx] = src[e];
}

// --------------------------- fused SAGE-1 (+ z projection) -----------------
__global__ __launch_bounds__(256) void sage1_fused(
    const float* __restrict__ h, const int* __restrict__ rp, const int* __restrict__ csr,
    const float* __restrict__ s1_self, const float* __restrict__ s1_neigh,
    const float* __restrict__ s1_b, const float* __restrict__ s2_neigh,
    float* __restrict__ h1, float* __restrict__ z16, int N)
{
    __shared__ float aggs[4][32];
    __shared__ float hl[4][64];
    const int t = threadIdx.x;
    const int nb = t >> 6, k = t & 63;
    const int n = blockIdx.x * 4 + nb;
    const int j = k & 31, half = k >> 5;

    int p0 = 0, p1 = 0;
    if (n < N) { p0 = rp[n]; p1 = rp[n + 1]; }
    float a = 0.f;
    for (int p = p0 + half; p < p1; p += 2)
        a += h[(size_t)csr[p] * 32 + j];
    a += __shfl_down(a, 32);
    if (half == 0) aggs[nb][j] = a;
    __syncthreads();

    float o = 0.f;
    if (n < N) {
        const int nu = __builtin_amdgcn_readfirstlane(n);
        float inv = 1.0f / fmaxf((float)(p1 - p0), 1.0f);
        o = s1_b[k];
#pragma unroll
        for (int jj = 0; jj < 32; ++jj) {
            o = fmaf(h[(size_t)nu * 32 + jj], s1_self[jj * 64 + k], o);
            o = fmaf(aggs[nb][jj] * inv, s1_neigh[jj * 64 + k], o);
        }
        o = fmaxf(o, 0.f);
        h1[(size_t)n * 64 + k] = o;
    }
    hl[nb][k] = o;
    __syncthreads();

    if (n < N && k < 16) {
        float z = 0.f;
        if (k < 10) {
#pragma unroll
            for (int jj = 0; jj < 64; ++jj) z = fmaf(hl[nb][jj], s2_neigh[jj * 10 + k], z);
        }
        z16[(size_t)n * 16 + k] = z;
    }
}

__global__ __launch_bounds__(256) void sage2_final_g(
    const float* __restrict__ h1, const float* __restrict__ z16,
    const int* __restrict__ rp, const int* __restrict__ csr,
    const float* __restrict__ s2_self, const float* __restrict__ s2_b,
    float* __restrict__ out, int N)
{
    int tid = blockIdx.x * 256 + threadIdx.x;
    int nn = tid >> 4, k = tid & 15;
    if (nn >= N || k >= 10) return;
    int p0 = rp[nn], p1 = rp[nn + 1];
    float a0 = 0.f, a1 = 0.f;
    int p = p0;
    for (; p + 2 <= p1; p += 2) {
        int s0 = csr[p], s1 = csr[p + 1];
        a0 += z16[(size_t)s0 * 16 + k];
        a1 += z16[(size_t)s1 * 16 + k];
    }
    if (p < p1) a0 += z16[(size_t)csr[p] * 16 + k];
    float inv = 1.0f / fmaxf((float)(p1 - p0), 1.0f);
    float o = s2_b[k] + (a0 + a1) * inv;
#pragma unroll
    for (int j = 0; j < 64; ++j) o = fmaf(h1[nn * 64 + j], s2_self[j * 10 + k], o);
    out[nn * 10 + k] = o;
}

extern "C" void kernel_launch(void* const* d_in, const int* in_sizes, int n_in,
                              void* d_out, int out_size, void* d_ws, size_t ws_size,
                              hipStream_t stream)
{
    const float* feat     = (const float*)d_in[0];
    const int*   src      = (const int*)d_in[1];
    const int*   dst      = (const int*)d_in[2];
    const float* conv_w   = (const float*)d_in[3];
    const float* conv_b   = (const float*)d_in[4];
    const float* w1       = (const float*)d_in[5];
    const float* b1       = (const float*)d_in[6];
    const float* w2       = (const float*)d_in[7];
    const float* b2       = (const float*)d_in[8];
    const float* s1_self  = (const float*)d_in[9];
    const float* s1_neigh = (const float*)d_in[10];
    const float* s1_b     = (const float*)d_in[11];
    const float* s2_self  = (const float*)d_in[12];
    const float* s2_neigh = (const float*)d_in[13];
    const float* s2_b     = (const float*)d_in[14];
    float* out = (float*)d_out;

    const int N = in_sizes[0] / 1280;  // 10000
    const int E = in_sizes[1];         // 320000
    const int NB_SCAN = (N + 255) / 256;  // 40

    // ws layout: [row_cnt N][h_fc1 32N]  <- contiguous, zeroed together
    char* wsb = (char*)d_ws;
    int*   row_cnt = (int*)wsb;                      wsb += (size_t)N * 4;
    float* h_fc1   = (float*)wsb;                    wsb += (size_t)N * 32 * 4;
    int*   excl    = (int*)wsb;                      wsb += (size_t)N * 4;
    int*   bsum    = (int*)wsb;                      wsb += 64 * 4;
    int*   bsumx   = (int*)wsb;                      wsb += 64 * 4;
    int*   row_ptr = (int*)wsb;                      wsb += (size_t)(N + 4) * 4;
    int*   cursor  = (int*)wsb;                      wsb += (size_t)N * 4;
    int*   csr     = (int*)wsb;                      wsb += (size_t)E * 4;
    float* h_cnn   = (float*)wsb;                    wsb += (size_t)N * 32 * 4;
    float* h1      = (float*)wsb;                    wsb += (size_t)N * 64 * 4;
    float* z16     = (float*)wsb;                    wsb += (size_t)N * 16 * 4;
    unsigned char* w1f = (unsigned char*)wsb;

    // zero row_cnt + h_fc1 (contiguous 33N words)
    zero_ws<<<(33 * N + 255) / 256, 256, 0, stream>>>((float*)row_cnt, 33 * N);

    // CSR build (3-kernel scan)
    count_deg<<<(E + 255) / 256, 256, 0, stream>>>(dst, row_cnt, E);
    scan_local<<<NB_SCAN, 256, 0, stream>>>(row_cnt, excl, bsum, N);
    scan_bsum<<<1, 64, 0, stream>>>(bsum, bsumx, row_ptr, NB_SCAN, N);
    scan_add<<<NB_SCAN, 256, 0, stream>>>(excl, bsumx, row_ptr, cursor, N);
    fill_csr<<<(E + 255) / 256, 256, 0, stream>>>(src, dst, cursor, csr, E);

    // CNN (1D grid 2500, XCD-chunked swizzle inside the kernel)
    w1_prep_v4<<<320, 256, 0, stream>>>(w1, w1f);
    cnn_fused_v17<<<(N / 16) * 4, 256, 0, stream>>>(feat, conv_w, conv_b, w1f, h_fc1);
    fc1_finish<<<(N + 7) / 8, 256, 0, stream>>>(h_fc1, b1, w2, b2, h_cnn, N);

    // SAGE 1 (gather + transform + z projection fused)
    sage1_fused<<<(N + 3) / 4, 256, 0, stream>>>(
        h_cnn, row_ptr, csr, s1_self, s1_neigh, s1_b, s2_neigh, h1, z16, N);

    // SAGE 2
    sage2_final_g<<<(int)(((size_t)N * 16 + 255) / 256), 256, 0, stream>>>(
        h1, z16, row_ptr, csr, s2_self, s2_b, out, N);
}

// Round 18
// 184.945 us; speedup vs baseline: 1.1714x; 1.0489x over previous
//
#include <hip/hip_runtime.h>

// ---------------------------------------------------------------------------
// GCN pipeline: CNN(conv3x3+relu+pool2x2+FC1+FC2) -> SAGE(mean) -> SAGE(mean)
// Round 18: R17 cnn unchanged. Tail: (1) sage1_fused gather unrolled 2x per
// half (4 edges in flight), (2) sage2_final 4-way unroll, (3) scan_bsum
// folded into scan_add (per-block in-wave prefix of bsum). FP-reorder only.
// ---------------------------------------------------------------------------

typedef __attribute__((ext_vector_type(8)))  short bf16x8;
typedef __attribute__((ext_vector_type(4)))  float f32x4;
typedef __attribute__((ext_vector_type(16))) float f32x16;

__device__ __forceinline__ unsigned short f2bf(float v) {
    union { float f; unsigned int u; } x; x.f = v;
    unsigned int r = x.u + 0x7FFFu + ((x.u >> 16) & 1u);  // RNE
    return (unsigned short)(r >> 16);
}
__device__ __forceinline__ float bf2f(unsigned short b) {
    union { float f; unsigned int u; } x; x.u = ((unsigned int)b) << 16;
    return x.f;
}
__device__ __forceinline__ unsigned cvtpk(float a, float b) {   // low16=bf(a), high16=bf(b)
    unsigned r;
    asm("v_cvt_pk_bf16_f32 %0, %1, %2" : "=v"(r) : "v"(a), "v"(b));
    return r;
}
__device__ __forceinline__ float lo2f(unsigned p) { union { unsigned u; float f; } x; x.u = p << 16; return x.f; }
__device__ __forceinline__ float hi2f(unsigned p) { union { unsigned u; float f; } x; x.u = p & 0xffff0000u; return x.f; }
__device__ __forceinline__ void split_pair(float a, float b, unsigned& hp, unsigned& lp) {
    hp = cvtpk(a, b);
    lp = cvtpk(a - lo2f(hp), b - hi2f(hp));
}

__global__ __launch_bounds__(256) void zero_ws(float* __restrict__ ws, int count) {
    int i = blockIdx.x * 256 + threadIdx.x;
    if (i < count) ws[i] = 0.0f;
}

// ---------------------------------------------------------------------------
// w1 prep (grid 320): fragment-ready bf16 hi/lo image per quarter (ph,qq).
// Within-unit position i maps to pwl: i<4 -> 2i, else 2(i-4)+1.
// ---------------------------------------------------------------------------
__global__ __launch_bounds__(256) void w1_prep_v4(
    const float* __restrict__ w1, unsigned char* __restrict__ w1f)
{
    int gu = blockIdx.x * 256 + threadIdx.x;   // 0..81919
    const int quarter = gu >> 11;
    const int u = gu & 2047;
    const int ph = quarter >> 2, qq = quarter & 3;
    const int ks   = u >> 8;
    const int jh   = (u >> 7) & 1;
    const int part = (u >> 6) & 1;
    const int lane = u & 63;
    const int j    = jh * 16 + (lane & 15);
    const int c    = ks * 4 + (lane >> 4);
    const int k0   = c * 320 + ph * 32 + qq * 8;
    unsigned short v[8];
#pragma unroll
    for (int i = 0; i < 8; ++i) {
        const int pwl_i = (i < 4) ? (2 * i) : (2 * (i - 4) + 1);
        float x = w1[(size_t)(k0 + pwl_i) * 32 + j];
        unsigned short h = f2bf(x);
        v[i] = part ? f2bf(x - bf2f(h)) : h;
    }
    *(uint4*)(w1f + (size_t)quarter * 32768 + (size_t)u * 16) = *(const uint4*)v;
}

// ---------------------------------------------------------------------------
// Fused CNN v17 (unchanged from R17): 16 nodes/block, 256 threads, 1D grid
// 2500, XCD-chunked bijective swizzle, single fc1A, 2 barriers/quarter,
// bias as K=9 tap, direct-b64 pool repack. LDS 34.8KB -> 4 blocks/CU.
// ---------------------------------------------------------------------------
__global__ __launch_bounds__(256, 4) void cnn_fused_v17(
    const float* __restrict__ feat,
    const float* __restrict__ conv_w, const float* __restrict__ conv_b,
    const unsigned char* __restrict__ w1f,
    float* __restrict__ h_fc1)
{
    __shared__ __align__(16) unsigned char convA[18432];
    __shared__ __align__(16) unsigned char fc1A[16384];   // single buffer

    // ---- XCD-chunked bijective swizzle (nwg=2500, q=312, r=4; m204 form)
    const int orig = blockIdx.x;
    const int c8 = orig & 7;
    const int wgid = (c8 < 4 ? c8 * 313 : 4 * 313 + (c8 - 4) * 312) + (orig >> 3);
    const int xg = wgid >> 2;         // node-group 0..624
    const int qq = wgid & 3;          // column slice 0..3

    const int t = threadIdx.x;
    const int wv = t >> 6;            // 0..3
    const int lane = t & 63;
    const int base = xg * 16;

    const int nn  = lane >> 4;
    const int pwl = lane & 7;
    const int aa  = (lane >> 3) & 1;
    const float* featn = feat + (size_t)(base + wv * 4 + nn) * 1280;

    const int pw = qq * 8 + pwl;      // fixed pooled col
    const int c0 = 2 * pw - 1;        // fixed input col window c0..c0+3
    const bool cv0 = (c0 >= 0);
    const bool cv3 = (c0 + 3 < 64);

    const int cch = lane & 31;
    const int ckg = lane >> 5;        // conv K-group AND output half h
    const int rowr = lane & 31;
    unsigned rsw = (unsigned)(rowr << 4); rsw ^= ((rsw >> 7) & 3u) << 4;

    // conv weight fragments; k=9 carries the bias (A-side k9 input is 1.0)
    bf16x8 cbh, cbl;
    {
        union { unsigned short u[8]; bf16x8 v; } H, L;
#pragma unroll
        for (int i = 0; i < 8; ++i) {
            int k = ckg * 8 + i;
            float x = (k < 9) ? conv_w[cch * 9 + k] : (k == 9 ? conv_b[cch] : 0.0f);
            unsigned short h = f2bf(x);
            H.u[i] = h; L.u[i] = f2bf(x - bf2f(h));
        }
        cbh = H.v; cbl = L.v;
    }

    const int nfr = lane & 15;
    const unsigned hoff = (unsigned)(ckg << 3);   // h*8: within-unit byte offset

    f32x4 acc0 = {0.f, 0.f, 0.f, 0.f};
    f32x4 acc1 = {0.f, 0.f, 0.f, 0.f};
    const f32x16 czero = {};    // hoisted zero C-operand

    float f0[4], f1[4], f2[4];
    auto load_row = [&](int r, float* o) {
        bool rv = (r >= 0) && (r < 20);
        const float* rp = featn + (rv ? r : 0) * 64;
        float2 m = *(const float2*)(rp + c0 + 1);    // c0+1 = 2pw: 8B-aligned, in-bounds
        float v0 = rp[cv0 ? c0 : 0];
        float v3 = rp[cv3 ? (c0 + 3) : 0];
        o[0] = (rv && cv0) ? v0 : 0.f;
        o[1] = rv ? m.x : 0.f;
        o[2] = rv ? m.y : 0.f;
        o[3] = (rv && cv3) ? v3 : 0.f;
    };

    load_row(aa - 1, f0);
    load_row(aa,     f1);
    load_row(aa + 1, f2);

#pragma unroll 1
    for (int ph = 0; ph < 10; ++ph) {
        const int quarter = ph * 4 + qq;
        unsigned char* fbuf = fc1A;

        // ---- (1) FC1 B-frags from global (L2); consumed in phase 4
        const unsigned char* wq = w1f + (size_t)quarter * 32768;
        bf16x8 bF[2][2][2];
#pragma unroll
        for (int si = 0; si < 2; ++si) {
            const int ks = wv + si * 4;
#pragma unroll
            for (int jh = 0; jh < 2; ++jh)
#pragma unroll
                for (int part = 0; part < 2; ++part)
                    bF[si][jh][part] = *(const bf16x8*)(
                        wq + (size_t)((((ks * 2 + jh) * 2 + part)) << 10) + lane * 16);
        }

        // ---- (2) split current rows -> convA + compact tap8
        {
            unsigned P[3][2], Q[3][2];
            split_pair(f0[0], f0[1], P[0][0], Q[0][0]);
            split_pair(f0[2], f0[3], P[0][1], Q[0][1]);
            split_pair(f1[0], f1[1], P[1][0], Q[1][0]);
            split_pair(f1[2], f1[3], P[1][1], Q[1][1]);
            split_pair(f2[0], f2[1], P[2][0], Q[2][0]);
            split_pair(f2[2], f2[3], P[2][1], Q[2][1]);

            const int r0 = pwl * 4 + aa * 2, r1 = r0 + 1;
            unsigned b0 = (unsigned)(r0 << 4); b0 ^= ((b0 >> 7) & 3u) << 4;
            unsigned b1 = (unsigned)(r1 << 4); b1 ^= ((b1 >> 7) & 3u) << 4;
            unsigned char* abw = convA + ((wv * 4 + nn) << 10);
            uint4 H0 = make_uint4(P[0][0],
                                  __builtin_amdgcn_perm(P[1][0], P[0][1], 0x05040100u),
                                  __builtin_amdgcn_perm(P[1][1], P[1][0], 0x05040302u),
                                  P[2][0]);
            uint4 H1 = make_uint4(__builtin_amdgcn_perm(P[0][1], P[0][0], 0x05040302u),
                                  __builtin_amdgcn_perm(P[1][0], P[0][1], 0x07060302u),
                                  P[1][1],
                                  __builtin_amdgcn_perm(P[2][1], P[2][0], 0x05040302u));
            uint4 L0 = make_uint4(Q[0][0],
                                  __builtin_amdgcn_perm(Q[1][0], Q[0][1], 0x05040100u),
                                  __builtin_amdgcn_perm(Q[1][1], Q[1][0], 0x05040302u),
                                  Q[2][0]);
            uint4 L1 = make_uint4(__builtin_amdgcn_perm(Q[0][1], Q[0][0], 0x05040302u),
                                  __builtin_amdgcn_perm(Q[1][0], Q[0][1], 0x07060302u),
                                  Q[1][1],
                                  __builtin_amdgcn_perm(Q[2][1], Q[2][0], 0x05040302u));
            *(uint4*)(abw + b0)       = H0;
            *(uint4*)(abw + b1)       = H1;
            *(uint4*)(abw + 512 + b0) = L0;
            *(uint4*)(abw + 512 + b1) = L1;
            unsigned wr0 = __builtin_amdgcn_perm(Q[2][1], P[2][1], 0x05040100u);
            unsigned wr1 = __builtin_amdgcn_perm(Q[2][1], P[2][1], 0x07060302u);
            *(uint2*)(convA + 16384 + (((wv * 4 + nn) * 32 + r0) << 2)) = make_uint2(wr0, wr1);
        }

        // ---- (2b) rotate window + prefetch next ph's two new rows
        if (ph < 9) {
#pragma unroll
            for (int j = 0; j < 4; ++j) f0[j] = f2[j];
            load_row(2 * ph + 2 + aa, f1);
            load_row(2 * ph + 3 + aa, f2);
        }

        // ---- (3) conv MFMA + in-lane pool + direct-b64 repack into fc1A
#pragma unroll
        for (int nn2 = 0; nn2 < 4; ++nn2) {
            bf16x8 a_h, a_l;
            if (ckg == 0) {
                const unsigned char* ab = convA + ((wv * 4 + nn2) << 10);
                a_h = *(const bf16x8*)(ab + rsw);
                a_l = *(const bf16x8*)(ab + 512 + rsw);
            } else {
                unsigned cw = *(const unsigned*)(convA + 16384 + (((wv * 4 + nn2) * 32 + rowr) << 2));
                // k=8: tap8 (hi/lo); k=9: constant 1.0 (bias tap; bf16(1.0)=0x3F80)
                a_h = (bf16x8){(short)(cw & 0xffffu), (short)0x3F80, 0, 0, 0, 0, 0, 0};
                a_l = (bf16x8){(short)(cw >> 16),     0,             0, 0, 0, 0, 0, 0};
            }
            f32x16 ca;
            ca = __builtin_amdgcn_mfma_f32_32x32x16_bf16(a_l, cbh, czero, 0, 0, 0);
            ca = __builtin_amdgcn_mfma_f32_32x32x16_bf16(a_h, cbl, ca, 0, 0, 0);
            ca = __builtin_amdgcn_mfma_f32_32x32x16_bf16(a_h, cbh, ca, 0, 0, 0);

            // bias already inside ca via k=9 tap; max(a+c,b+c)=max(a,b)+c
            // lane (cch, h=ckg) holds pooled values for pwl = 2i + h, i=0..3
            float pv0 = fmaxf(fmaxf(fmaxf(ca[0],  ca[1]),  fmaxf(ca[2],  ca[3])),  0.f);
            float pv1 = fmaxf(fmaxf(fmaxf(ca[4],  ca[5]),  fmaxf(ca[6],  ca[7])),  0.f);
            float pv2 = fmaxf(fmaxf(fmaxf(ca[8],  ca[9]),  fmaxf(ca[10], ca[11])), 0.f);
            float pv3 = fmaxf(fmaxf(fmaxf(ca[12], ca[13]), fmaxf(ca[14], ca[15])), 0.f);

            unsigned ha, la, hb, lb;
            split_pair(pv0, pv1, ha, la);
            split_pair(pv2, pv3, hb, lb);

            const int nloc = wv * 4 + nn2;
            const int ksW = cch >> 2, kgW = cch & 3;
            unsigned bh = (unsigned)((((0 * 8 + ksW) * 64) + kgW * 16 + nloc) << 4);
            bh ^= ((bh >> 8) & 7u) << 4;
            unsigned bl = (unsigned)((((1 * 8 + ksW) * 64) + kgW * 16 + nloc) << 4);
            bl ^= ((bl >> 8) & 7u) << 4;
            *(uint2*)(fbuf + bh + hoff) = make_uint2(ha, hb);
            *(uint2*)(fbuf + bl + hoff) = make_uint2(la, lb);
        }

        __syncthreads();   // fc1A writes visible to all waves

        // ---- (4) FC1 MFMA: wave wv handles ksteps {wv, wv+4}
#pragma unroll
        for (int si = 0; si < 2; ++si) {
            const int ks = wv + si * 4;
            unsigned bH = (unsigned)(((0 * 8 + ks) << 10) + lane * 16); bH ^= ((bH >> 8) & 7u) << 4;
            unsigned bL = (unsigned)(((1 * 8 + ks) << 10) + lane * 16); bL ^= ((bL >> 8) & 7u) << 4;
            bf16x8 fa_h = *(const bf16x8*)(fbuf + bH);
            bf16x8 fa_l = *(const bf16x8*)(fbuf + bL);
            acc0 = __builtin_amdgcn_mfma_f32_16x16x32_bf16(fa_l, bF[si][0][0], acc0, 0, 0, 0);
            acc0 = __builtin_amdgcn_mfma_f32_16x16x32_bf16(fa_h, bF[si][0][1], acc0, 0, 0, 0);
            acc0 = __builtin_amdgcn_mfma_f32_16x16x32_bf16(fa_h, bF[si][0][0], acc0, 0, 0, 0);
            acc1 = __builtin_amdgcn_mfma_f32_16x16x32_bf16(fa_l, bF[si][1][0], acc1, 0, 0, 0);
            acc1 = __builtin_amdgcn_mfma_f32_16x16x32_bf16(fa_h, bF[si][1][1], acc1, 0, 0, 0);
            acc1 = __builtin_amdgcn_mfma_f32_16x16x32_bf16(fa_h, bF[si][1][0], acc1, 0, 0, 0);
        }

        __syncthreads();   // all waves done reading fc1A before next quarter's writes
    }

    // ---- epilogue: cross-wave reduce (overlay on convA) + atomic FC1 partials
    float* red = (float*)convA;
#pragma unroll
    for (int r = 0; r < 4; ++r) {
        int node = (lane >> 4) * 4 + r;
        red[wv * 512 + node * 32 + nfr]      = acc0[r];
        red[wv * 512 + node * 32 + 16 + nfr] = acc1[r];
    }
    __syncthreads();
    {
        const int en = t >> 4, jp = t & 15;
        const int j0 = 2 * jp;
        float s0 = 0.f, s1 = 0.f;
#pragma unroll
        for (int wi = 0; wi < 4; ++wi) {
            s0 += red[wi * 512 + en * 32 + j0];
            s1 += red[wi * 512 + en * 32 + j0 + 1];
        }
        atomicAdd(&h_fc1[(size_t)(base + en) * 32 + j0],     s0);
        atomicAdd(&h_fc1[(size_t)(base + en) * 32 + j0 + 1], s1);
    }
}

// h_fc1 -> +b1, relu, FC2(+b2), relu -> h_cnn
__global__ __launch_bounds__(256) void fc1_finish(
    const float* __restrict__ h_fc1, const float* __restrict__ b1,
    const float* __restrict__ w2, const float* __restrict__ b2,
    float* __restrict__ h_out, int N)
{
    __shared__ float hr[8][32];
    const int t = threadIdx.x;
    const int nb = t >> 5, j = t & 31;
    const int n = blockIdx.x * 8 + nb;
    if (n < N) hr[nb][j] = fmaxf(h_fc1[(size_t)n * 32 + j] + b1[j], 0.f);
    __syncthreads();
    if (n >= N) return;
    float o = b2[j];
#pragma unroll
    for (int k = 0; k < 32; ++k) o = fmaf(hr[nb][k], w2[k * 32 + j], o);
    h_out[(size_t)n * 32 + j] = fmaxf(o, 0.f);
}

// --------------------------- CSR build -------------------------------------
__global__ __launch_bounds__(256) void count_deg(
    const int* __restrict__ dst, int* __restrict__ cnt, int E)
{
    int e = blockIdx.x * 256 + threadIdx.x;
    if (e < E) atomicAdd(&cnt[dst[e]], 1);
}

__global__ __launch_bounds__(256) void scan_local(
    const int* __restrict__ cnt, int* __restrict__ excl, int* __restrict__ bsum, int N)
{
    __shared__ int s[256];
    int t = threadIdx.x, b = blockIdx.x, i = b * 256 + t;
    int v = (i < N) ? cnt[i] : 0;
    s[t] = v;
    __syncthreads();
#pragma unroll
    for (int off = 1; off < 256; off <<= 1) {
        int x = (t >= off) ? s[t - off] : 0;
        __syncthreads();
        s[t] += x;
        __syncthreads();
    }
    int incl = s[t];
    if (i < N) excl[i] = incl - v;
    if (t == 255) bsum[b] = incl;
}

// scan_add with in-block bsum prefix (replaces scan_bsum + scan_add)
__global__ __launch_bounds__(256) void scan_add2(
    const int* __restrict__ excl, const int* __restrict__ bsum,
    int* __restrict__ row_ptr, int* __restrict__ cursor, int N, int nb)
{
    __shared__ int spref;
    const int t = threadIdx.x, b = blockIdx.x;
    if (t < 64) {
        int v = (t < b) ? bsum[t] : 0;   // nb <= 64
#pragma unroll
        for (int off = 32; off > 0; off >>= 1) v += __shfl_down(v, off);
        if (t == 0) spref = v;
    }
    __syncthreads();
    const int pref = spref;
    int i = b * 256 + t;
    if (i < N) {
        int rp = excl[i] + pref;
        row_ptr[i] = rp;
        cursor[i]  = rp;
    }
    if (b == nb - 1 && t == 0) row_ptr[N] = pref + bsum[b];   // == E
}

__global__ __launch_bounds__(256) void fill_csr(
    const int* __restrict__ src, const int* __restrict__ dst,
    int* __restrict__ cursor, int* __restrict__ csr, int E)
{
    int e = blockIdx.x * 256 + threadIdx.x;
    if (e >= E) return;
    int idx = atomicAdd(&cursor[dst[e]], 1);
    csr[idx] = src[e];
}

// --------------------------- fused SAGE-1 (+ z projection) -----------------
// gather: 2 lane-halves x 2-way unroll = 4 edges in flight per node.
__global__ __launch_bounds__(256) void sage1_fused(
    const float* __restrict__ h, const int* __restrict__ rp, const int* __restrict__ csr,
    const float* __restrict__ s1_self, const float* __restrict__ s1_neigh,
    const float* __restrict__ s1_b, const float* __restrict__ s2_neigh,
    float* __restrict__ h1, float* __restrict__ z16, int N)
{
    __shared__ float aggs[4][32];
    __shared__ float hl[4][64];
    const int t = threadIdx.x;
    const int nb = t >> 6, k = t & 63;
    const int n = blockIdx.x * 4 + nb;
    const int j = k & 31, half = k >> 5;

    int p0 = 0, p1 = 0;
    if (n < N) { p0 = rp[n]; p1 = rp[n + 1]; }
    float a0 = 0.f, a1 = 0.f;
    int p = p0 + half;
    for (; p + 2 < p1; p += 4) {          // edges p and p+2 both valid
        int s0 = csr[p], s1 = csr[p + 2];
        a0 += h[(size_t)s0 * 32 + j];
        a1 += h[(size_t)s1 * 32 + j];
    }
    if (p < p1) a0 += h[(size_t)csr[p] * 32 + j];
    float a = a0 + a1;
    a += __shfl_down(a, 32);
    if (half == 0) aggs[nb][j] = a;
    __syncthreads();

    float o = 0.f;
    if (n < N) {
        const int nu = __builtin_amdgcn_readfirstlane(n);
        float inv = 1.0f / fmaxf((float)(p1 - p0), 1.0f);
        o = s1_b[k];
#pragma unroll
        for (int jj = 0; jj < 32; ++jj) {
            o = fmaf(h[(size_t)nu * 32 + jj], s1_self[jj * 64 + k], o);
            o = fmaf(aggs[nb][jj] * inv, s1_neigh[jj * 64 + k], o);
        }
        o = fmaxf(o, 0.f);
        h1[(size_t)n * 64 + k] = o;
    }
    hl[nb][k] = o;
    __syncthreads();

    if (n < N && k < 16) {
        float z = 0.f;
        if (k < 10) {
#pragma unroll
            for (int jj = 0; jj < 64; ++jj) z = fmaf(hl[nb][jj], s2_neigh[jj * 10 + k], z);
        }
        z16[(size_t)n * 16 + k] = z;
    }
}

__global__ __launch_bounds__(256) void sage2_final_g(
    const float* __restrict__ h1, const float* __restrict__ z16,
    const int* __restrict__ rp, const int* __restrict__ csr,
    const float* __restrict__ s2_self, const float* __restrict__ s2_b,
    float* __restrict__ out, int N)
{
    int tid = blockIdx.x * 256 + threadIdx.x;
    int nn = tid >> 4, k = tid & 15;
    if (nn >= N || k >= 10) return;
    int p0 = rp[nn], p1 = rp[nn + 1];
    float a0 = 0.f, a1 = 0.f, a2 = 0.f, a3 = 0.f;
    int p = p0;
    for (; p + 4 <= p1; p += 4) {
        int s0 = csr[p], s1 = csr[p + 1], s2 = csr[p + 2], s3 = csr[p + 3];
        a0 += z16[(size_t)s0 * 16 + k];
        a1 += z16[(size_t)s1 * 16 + k];
        a2 += z16[(size_t)s2 * 16 + k];
        a3 += z16[(size_t)s3 * 16 + k];
    }
    for (; p < p1; ++p) a0 += z16[(size_t)csr[p] * 16 + k];
    float inv = 1.0f / fmaxf((float)(p1 - p0), 1.0f);
    float o = s2_b[k] + ((a0 + a1) + (a2 + a3)) * inv;
#pragma unroll
    for (int j = 0; j < 64; ++j) o = fmaf(h1[nn * 64 + j], s2_self[j * 10 + k], o);
    out[nn * 10 + k] = o;
}

extern "C" void kernel_launch(void* const* d_in, const int* in_sizes, int n_in,
                              void* d_out, int out_size, void* d_ws, size_t ws_size,
                              hipStream_t stream)
{
    const float* feat     = (const float*)d_in[0];
    const int*   src      = (const int*)d_in[1];
    const int*   dst      = (const int*)d_in[2];
    const float* conv_w   = (const float*)d_in[3];
    const float* conv_b   = (const float*)d_in[4];
    const float* w1       = (const float*)d_in[5];
    const float* b1       = (const float*)d_in[6];
    const float* w2       = (const float*)d_in[7];
    const float* b2       = (const float*)d_in[8];
    const float* s1_self  = (const float*)d_in[9];
    const float* s1_neigh = (const float*)d_in[10];
    const float* s1_b     = (const float*)d_in[11];
    const float* s2_self  = (const float*)d_in[12];
    const float* s2_neigh = (const float*)d_in[13];
    const float* s2_b     = (const float*)d_in[14];
    float* out = (float*)d_out;

    const int N = in_sizes[0] / 1280;  // 10000
    const int E = in_sizes[1];         // 320000
    const int NB_SCAN = (N + 255) / 256;  // 40

    // ws layout: [row_cnt N][h_fc1 32N]  <- contiguous, zeroed together
    char* wsb = (char*)d_ws;
    int*   row_cnt = (int*)wsb;                      wsb += (size_t)N * 4;
    float* h_fc1   = (float*)wsb;                    wsb += (size_t)N * 32 * 4;
    int*   excl    = (int*)wsb;                      wsb += (size_t)N * 4;
    int*   bsum    = (int*)wsb;                      wsb += 64 * 4;
    int*   row_ptr = (int*)wsb;                      wsb += (size_t)(N + 4) * 4;
    int*   cursor  = (int*)wsb;                      wsb += (size_t)N * 4;
    int*   csr     = (int*)wsb;                      wsb += (size_t)E * 4;
    float* h_cnn   = (float*)wsb;                    wsb += (size_t)N * 32 * 4;
    float* h1      = (float*)wsb;                    wsb += (size_t)N * 64 * 4;
    float* z16     = (float*)wsb;                    wsb += (size_t)N * 16 * 4;
    unsigned char* w1f = (unsigned char*)wsb;

    // zero row_cnt + h_fc1 (contiguous 33N words)
    zero_ws<<<(33 * N + 255) / 256, 256, 0, stream>>>((float*)row_cnt, 33 * N);

    // CSR build (2-kernel scan)
    count_deg<<<(E + 255) / 256, 256, 0, stream>>>(dst, row_cnt, E);
    scan_local<<<NB_SCAN, 256, 0, stream>>>(row_cnt, excl, bsum, N);
    scan_add2<<<NB_SCAN, 256, 0, stream>>>(excl, bsum, row_ptr, cursor, N, NB_SCAN);
    fill_csr<<<(E + 255) / 256, 256, 0, stream>>>(src, dst, cursor, csr, E);

    // CNN (1D grid 2500, XCD-chunked swizzle inside the kernel)
    w1_prep_v4<<<320, 256, 0, stream>>>(w1, w1f);
    cnn_fused_v17<<<(N / 16) * 4, 256, 0, stream>>>(feat, conv_w, conv_b, w1f, h_fc1);
    fc1_finish<<<(N + 7) / 8, 256, 0, stream>>>(h_fc1, b1, w2, b2, h_cnn, N);

    // SAGE 1 (gather + transform + z projection fused)
    sage1_fused<<<(N + 3) / 4, 256, 0, stream>>>(
        h_cnn, row_ptr, csr, s1_self, s1_neigh, s1_b, s2_neigh, h1, z16, N);

    // SAGE 2
    sage2_final_g<<<(int)(((size_t)N * 16 + 255) / 256), 256, 0, stream>>>(
        h1, z16, row_ptr, csr, s2_self, s2_b, out, N);
}

// Round 19
// 182.607 us; speedup vs baseline: 1.1864x; 1.0128x over previous
//
#include <hip/hip_runtime.h>

// ---------------------------------------------------------------------------
// GCN pipeline: CNN(conv3x3+relu+pool2x2+FC1+FC2) -> SAGE(mean) -> SAGE(mean)
// Round 19: (1) sage1_fused gather unrolled 4x per half (8 edges in flight);
// (2) s_setprio(1) around cnn MFMA clusters (4 independent blocks/CU ->
// scheduler phase diversity, T5 regime). Everything else == R18.
// ---------------------------------------------------------------------------

typedef __attribute__((ext_vector_type(8)))  short bf16x8;
typedef __attribute__((ext_vector_type(4)))  float f32x4;
typedef __attribute__((ext_vector_type(16))) float f32x16;

__device__ __forceinline__ unsigned short f2bf(float v) {
    union { float f; unsigned int u; } x; x.f = v;
    unsigned int r = x.u + 0x7FFFu + ((x.u >> 16) & 1u);  // RNE
    return (unsigned short)(r >> 16);
}
__device__ __forceinline__ float bf2f(unsigned short b) {
    union { float f; unsigned int u; } x; x.u = ((unsigned int)b) << 16;
    return x.f;
}
__device__ __forceinline__ unsigned cvtpk(float a, float b) {   // low16=bf(a), high16=bf(b)
    unsigned r;
    asm("v_cvt_pk_bf16_f32 %0, %1, %2" : "=v"(r) : "v"(a), "v"(b));
    return r;
}
__device__ __forceinline__ float lo2f(unsigned p) { union { unsigned u; float f; } x; x.u = p << 16; return x.f; }
__device__ __forceinline__ float hi2f(unsigned p) { union { unsigned u; float f; } x; x.u = p & 0xffff0000u; return x.f; }
__device__ __forceinline__ void split_pair(float a, float b, unsigned& hp, unsigned& lp) {
    hp = cvtpk(a, b);
    lp = cvtpk(a - lo2f(hp), b - hi2f(hp));
}

__global__ __launch_bounds__(256) void zero_ws(float* __restrict__ ws, int count) {
    int i = blockIdx.x * 256 + threadIdx.x;
    if (i < count) ws[i] = 0.0f;
}

// ---------------------------------------------------------------------------
// w1 prep (grid 320): fragment-ready bf16 hi/lo image per quarter (ph,qq).
// Within-unit position i maps to pwl: i<4 -> 2i, else 2(i-4)+1.
// ---------------------------------------------------------------------------
__global__ __launch_bounds__(256) void w1_prep_v4(
    const float* __restrict__ w1, unsigned char* __restrict__ w1f)
{
    int gu = blockIdx.x * 256 + threadIdx.x;   // 0..81919
    const int quarter = gu >> 11;
    const int u = gu & 2047;
    const int ph = quarter >> 2, qq = quarter & 3;
    const int ks   = u >> 8;
    const int jh   = (u >> 7) & 1;
    const int part = (u >> 6) & 1;
    const int lane = u & 63;
    const int j    = jh * 16 + (lane & 15);
    const int c    = ks * 4 + (lane >> 4);
    const int k0   = c * 320 + ph * 32 + qq * 8;
    unsigned short v[8];
#pragma unroll
    for (int i = 0; i < 8; ++i) {
        const int pwl_i = (i < 4) ? (2 * i) : (2 * (i - 4) + 1);
        float x = w1[(size_t)(k0 + pwl_i) * 32 + j];
        unsigned short h = f2bf(x);
        v[i] = part ? f2bf(x - bf2f(h)) : h;
    }
    *(uint4*)(w1f + (size_t)quarter * 32768 + (size_t)u * 16) = *(const uint4*)v;
}

// ---------------------------------------------------------------------------
// Fused CNN v19: == v17 + s_setprio(1) around the MFMA clusters.
// 16 nodes/block, 256 threads, 1D grid 2500, XCD-chunked bijective swizzle,
// single fc1A, 2 barriers/quarter, bias as K=9 tap, direct-b64 pool repack.
// LDS 34.8KB -> 4 blocks/CU.
// ---------------------------------------------------------------------------
__global__ __launch_bounds__(256, 4) void cnn_fused_v19(
    const float* __restrict__ feat,
    const float* __restrict__ conv_w, const float* __restrict__ conv_b,
    const unsigned char* __restrict__ w1f,
    float* __restrict__ h_fc1)
{
    __shared__ __align__(16) unsigned char convA[18432];
    __shared__ __align__(16) unsigned char fc1A[16384];   // single buffer

    // ---- XCD-chunked bijective swizzle (nwg=2500, q=312, r=4; m204 form)
    const int orig = blockIdx.x;
    const int c8 = orig & 7;
    const int wgid = (c8 < 4 ? c8 * 313 : 4 * 313 + (c8 - 4) * 312) + (orig >> 3);
    const int xg = wgid >> 2;         // node-group 0..624
    const int qq = wgid & 3;          // column slice 0..3

    const int t = threadIdx.x;
    const int wv = t >> 6;            // 0..3
    const int lane = t & 63;
    const int base = xg * 16;

    const int nn  = lane >> 4;
    const int pwl = lane & 7;
    const int aa  = (lane >> 3) & 1;
    const float* featn = feat + (size_t)(base + wv * 4 + nn) * 1280;

    const int pw = qq * 8 + pwl;      // fixed pooled col
    const int c0 = 2 * pw - 1;        // fixed input col window c0..c0+3
    const bool cv0 = (c0 >= 0);
    const bool cv3 = (c0 + 3 < 64);

    const int cch = lane & 31;
    const int ckg = lane >> 5;        // conv K-group AND output half h
    const int rowr = lane & 31;
    unsigned rsw = (unsigned)(rowr << 4); rsw ^= ((rsw >> 7) & 3u) << 4;

    // conv weight fragments; k=9 carries the bias (A-side k9 input is 1.0)
    bf16x8 cbh, cbl;
    {
        union { unsigned short u[8]; bf16x8 v; } H, L;
#pragma unroll
        for (int i = 0; i < 8; ++i) {
            int k = ckg * 8 + i;
            float x = (k < 9) ? conv_w[cch * 9 + k] : (k == 9 ? conv_b[cch] : 0.0f);
            unsigned short h = f2bf(x);
            H.u[i] = h; L.u[i] = f2bf(x - bf2f(h));
        }
        cbh = H.v; cbl = L.v;
    }

    const int nfr = lane & 15;
    const unsigned hoff = (unsigned)(ckg << 3);   // h*8: within-unit byte offset

    f32x4 acc0 = {0.f, 0.f, 0.f, 0.f};
    f32x4 acc1 = {0.f, 0.f, 0.f, 0.f};
    const f32x16 czero = {};    // hoisted zero C-operand

    float f0[4], f1[4], f2[4];
    auto load_row = [&](int r, float* o) {
        bool rv = (r >= 0) && (r < 20);
        const float* rp = featn + (rv ? r : 0) * 64;
        float2 m = *(const float2*)(rp + c0 + 1);    // c0+1 = 2pw: 8B-aligned, in-bounds
        float v0 = rp[cv0 ? c0 : 0];
        float v3 = rp[cv3 ? (c0 + 3) : 0];
        o[0] = (rv && cv0) ? v0 : 0.f;
        o[1] = rv ? m.x : 0.f;
        o[2] = rv ? m.y : 0.f;
        o[3] = (rv && cv3) ? v3 : 0.f;
    };

    load_row(aa - 1, f0);
    load_row(aa,     f1);
    load_row(aa + 1, f2);

#pragma unroll 1
    for (int ph = 0; ph < 10; ++ph) {
        const int quarter = ph * 4 + qq;
        unsigned char* fbuf = fc1A;

        // ---- (1) FC1 B-frags from global (L2); consumed in phase 4
        const unsigned char* wq = w1f + (size_t)quarter * 32768;
        bf16x8 bF[2][2][2];
#pragma unroll
        for (int si = 0; si < 2; ++si) {
            const int ks = wv + si * 4;
#pragma unroll
            for (int jh = 0; jh < 2; ++jh)
#pragma unroll
                for (int part = 0; part < 2; ++part)
                    bF[si][jh][part] = *(const bf16x8*)(
                        wq + (size_t)((((ks * 2 + jh) * 2 + part)) << 10) + lane * 16);
        }

        // ---- (2) split current rows -> convA + compact tap8
        {
            unsigned P[3][2], Q[3][2];
            split_pair(f0[0], f0[1], P[0][0], Q[0][0]);
            split_pair(f0[2], f0[3], P[0][1], Q[0][1]);
            split_pair(f1[0], f1[1], P[1][0], Q[1][0]);
            split_pair(f1[2], f1[3], P[1][1], Q[1][1]);
            split_pair(f2[0], f2[1], P[2][0], Q[2][0]);
            split_pair(f2[2], f2[3], P[2][1], Q[2][1]);

            const int r0 = pwl * 4 + aa * 2, r1 = r0 + 1;
            unsigned b0 = (unsigned)(r0 << 4); b0 ^= ((b0 >> 7) & 3u) << 4;
            unsigned b1 = (unsigned)(r1 << 4); b1 ^= ((b1 >> 7) & 3u) << 4;
            unsigned char* abw = convA + ((wv * 4 + nn) << 10);
            uint4 H0 = make_uint4(P[0][0],
                                  __builtin_amdgcn_perm(P[1][0], P[0][1], 0x05040100u),
                                  __builtin_amdgcn_perm(P[1][1], P[1][0], 0x05040302u),
                                  P[2][0]);
            uint4 H1 = make_uint4(__builtin_amdgcn_perm(P[0][1], P[0][0], 0x05040302u),
                                  __builtin_amdgcn_perm(P[1][0], P[0][1], 0x07060302u),
                                  P[1][1],
                                  __builtin_amdgcn_perm(P[2][1], P[2][0], 0x05040302u));
            uint4 L0 = make_uint4(Q[0][0],
                                  __builtin_amdgcn_perm(Q[1][0], Q[0][1], 0x05040100u),
                                  __builtin_amdgcn_perm(Q[1][1], Q[1][0], 0x05040302u),
                                  Q[2][0]);
            uint4 L1 = make_uint4(__builtin_amdgcn_perm(Q[0][1], Q[0][0], 0x05040302u),
                                  __builtin_amdgcn_perm(Q[1][0], Q[0][1], 0x07060302u),
                                  Q[1][1],
                                  __builtin_amdgcn_perm(Q[2][1], Q[2][0], 0x05040302u));
            *(uint4*)(abw + b0)       = H0;
            *(uint4*)(abw + b1)       = H1;
            *(uint4*)(abw + 512 + b0) = L0;
            *(uint4*)(abw + 512 + b1) = L1;
            unsigned wr0 = __builtin_amdgcn_perm(Q[2][1], P[2][1], 0x05040100u);
            unsigned wr1 = __builtin_amdgcn_perm(Q[2][1], P[2][1], 0x07060302u);
            *(uint2*)(convA + 16384 + (((wv * 4 + nn) * 32 + r0) << 2)) = make_uint2(wr0, wr1);
        }

        // ---- (2b) rotate window + prefetch next ph's two new rows
        if (ph < 9) {
#pragma unroll
            for (int j = 0; j < 4; ++j) f0[j] = f2[j];
            load_row(2 * ph + 2 + aa, f1);
            load_row(2 * ph + 3 + aa, f2);
        }

        // ---- (3) conv MFMA + in-lane pool + direct-b64 repack into fc1A
#pragma unroll
        for (int nn2 = 0; nn2 < 4; ++nn2) {
            bf16x8 a_h, a_l;
            if (ckg == 0) {
                const unsigned char* ab = convA + ((wv * 4 + nn2) << 10);
                a_h = *(const bf16x8*)(ab + rsw);
                a_l = *(const bf16x8*)(ab + 512 + rsw);
            } else {
                unsigned cw = *(const unsigned*)(convA + 16384 + (((wv * 4 + nn2) * 32 + rowr) << 2));
                // k=8: tap8 (hi/lo); k=9: constant 1.0 (bias tap; bf16(1.0)=0x3F80)
                a_h = (bf16x8){(short)(cw & 0xffffu), (short)0x3F80, 0, 0, 0, 0, 0, 0};
                a_l = (bf16x8){(short)(cw >> 16),     0,             0, 0, 0, 0, 0, 0};
            }
            f32x16 ca;
            __builtin_amdgcn_s_setprio(1);
            ca = __builtin_amdgcn_mfma_f32_32x32x16_bf16(a_l, cbh, czero, 0, 0, 0);
            ca = __builtin_amdgcn_mfma_f32_32x32x16_bf16(a_h, cbl, ca, 0, 0, 0);
            ca = __builtin_amdgcn_mfma_f32_32x32x16_bf16(a_h, cbh, ca, 0, 0, 0);
            __builtin_amdgcn_s_setprio(0);

            // bias already inside ca via k=9 tap; max(a+c,b+c)=max(a,b)+c
            // lane (cch, h=ckg) holds pooled values for pwl = 2i + h, i=0..3
            float pv0 = fmaxf(fmaxf(fmaxf(ca[0],  ca[1]),  fmaxf(ca[2],  ca[3])),  0.f);
            float pv1 = fmaxf(fmaxf(fmaxf(ca[4],  ca[5]),  fmaxf(ca[6],  ca[7])),  0.f);
            float pv2 = fmaxf(fmaxf(fmaxf(ca[8],  ca[9]),  fmaxf(ca[10], ca[11])), 0.f);
            float pv3 = fmaxf(fmaxf(fmaxf(ca[12], ca[13]), fmaxf(ca[14], ca[15])), 0.f);

            unsigned ha, la, hb, lb;
            split_pair(pv0, pv1, ha, la);
            split_pair(pv2, pv3, hb, lb);

            const int nloc = wv * 4 + nn2;
            const int ksW = cch >> 2, kgW = cch & 3;
            unsigned bh = (unsigned)((((0 * 8 + ksW) * 64) + kgW * 16 + nloc) << 4);
            bh ^= ((bh >> 8) & 7u) << 4;
            unsigned bl = (unsigned)((((1 * 8 + ksW) * 64) + kgW * 16 + nloc) << 4);
            bl ^= ((bl >> 8) & 7u) << 4;
            *(uint2*)(fbuf + bh + hoff) = make_uint2(ha, hb);
            *(uint2*)(fbuf + bl + hoff) = make_uint2(la, lb);
        }

        __syncthreads();   // fc1A writes visible to all waves

        // ---- (4) FC1 MFMA: wave wv handles ksteps {wv, wv+4}
        __builtin_amdgcn_s_setprio(1);
#pragma unroll
        for (int si = 0; si < 2; ++si) {
            const int ks = wv + si * 4;
            unsigned bH = (unsigned)(((0 * 8 + ks) << 10) + lane * 16); bH ^= ((bH >> 8) & 7u) << 4;
            unsigned bL = (unsigned)(((1 * 8 + ks) << 10) + lane * 16); bL ^= ((bL >> 8) & 7u) << 4;
            bf16x8 fa_h = *(const bf16x8*)(fbuf + bH);
            bf16x8 fa_l = *(const bf16x8*)(fbuf + bL);
            acc0 = __builtin_amdgcn_mfma_f32_16x16x32_bf16(fa_l, bF[si][0][0], acc0, 0, 0, 0);
            acc0 = __builtin_amdgcn_mfma_f32_16x16x32_bf16(fa_h, bF[si][0][1], acc0, 0, 0, 0);
            acc0 = __builtin_amdgcn_mfma_f32_16x16x32_bf16(fa_h, bF[si][0][0], acc0, 0, 0, 0);
            acc1 = __builtin_amdgcn_mfma_f32_16x16x32_bf16(fa_l, bF[si][1][0], acc1, 0, 0, 0);
            acc1 = __builtin_amdgcn_mfma_f32_16x16x32_bf16(fa_h, bF[si][1][1], acc1, 0, 0, 0);
            acc1 = __builtin_amdgcn_mfma_f32_16x16x32_bf16(fa_h, bF[si][1][0], acc1, 0, 0, 0);
        }
        __builtin_amdgcn_s_setprio(0);

        __syncthreads();   // all waves done reading fc1A before next quarter's writes
    }

    // ---- epilogue: cross-wave reduce (overlay on convA) + atomic FC1 partials
    float* red = (float*)convA;
#pragma unroll
    for (int r = 0; r < 4; ++r) {
        int node = (lane >> 4) * 4 + r;
        red[wv * 512 + node * 32 + nfr]      = acc0[r];
        red[wv * 512 + node * 32 + 16 + nfr] = acc1[r];
    }
    __syncthreads();
    {
        const int en = t >> 4, jp = t & 15;
        const int j0 = 2 * jp;
        float s0 = 0.f, s1 = 0.f;
#pragma unroll
        for (int wi = 0; wi < 4; ++wi) {
            s0 += red[wi * 512 + en * 32 + j0];
            s1 += red[wi * 512 + en * 32 + j0 + 1];
        }
        atomicAdd(&h_fc1[(size_t)(base + en) * 32 + j0],     s0);
        atomicAdd(&h_fc1[(size_t)(base + en) * 32 + j0 + 1], s1);
    }
}

// h_fc1 -> +b1, relu, FC2(+b2), relu -> h_cnn
__global__ __launch_bounds__(256) void fc1_finish(
    const float* __restrict__ h_fc1, const float* __restrict__ b1,
    const float* __restrict__ w2, const float* __restrict__ b2,
    float* __restrict__ h_out, int N)
{
    __shared__ float hr[8][32];
    const int t = threadIdx.x;
    const int nb = t >> 5, j = t & 31;
    const int n = blockIdx.x * 8 + nb;
    if (n < N) hr[nb][j] = fmaxf(h_fc1[(size_t)n * 32 + j] + b1[j], 0.f);
    __syncthreads();
    if (n >= N) return;
    float o = b2[j];
#pragma unroll
    for (int k = 0; k < 32; ++k) o = fmaf(hr[nb][k], w2[k * 32 + j], o);
    h_out[(size_t)n * 32 + j] = fmaxf(o, 0.f);
}

// --------------------------- CSR build -------------------------------------
__global__ __launch_bounds__(256) void count_deg(
    const int* __restrict__ dst, int* __restrict__ cnt, int E)
{
    int e = blockIdx.x * 256 + threadIdx.x;
    if (e < E) atomicAdd(&cnt[dst[e]], 1);
}

__global__ __launch_bounds__(256) void scan_local(
    const int* __restrict__ cnt, int* __restrict__ excl, int* __restrict__ bsum, int N)
{
    __shared__ int s[256];
    int t = threadIdx.x, b = blockIdx.x, i = b * 256 + t;
    int v = (i < N) ? cnt[i] : 0;
    s[t] = v;
    __syncthreads();
#pragma unroll
    for (int off = 1; off < 256; off <<= 1) {
        int x = (t >= off) ? s[t - off] : 0;
        __syncthreads();
        s[t] += x;
        __syncthreads();
    }
    int incl = s[t];
    if (i < N) excl[i] = incl - v;
    if (t == 255) bsum[b] = incl;
}

// scan_add with in-block bsum prefix (replaces scan_bsum + scan_add)
__global__ __launch_bounds__(256) void scan_add2(
    const int* __restrict__ excl, const int* __restrict__ bsum,
    int* __restrict__ row_ptr, int* __restrict__ cursor, int N, int nb)
{
    __shared__ int spref;
    const int t = threadIdx.x, b = blockIdx.x;
    if (t < 64) {
        int v = (t < b) ? bsum[t] : 0;   // nb <= 64
#pragma unroll
        for (int off = 32; off > 0; off >>= 1) v += __shfl_down(v, off);
        if (t == 0) spref = v;
    }
    __syncthreads();
    const int pref = spref;
    int i = b * 256 + t;
    if (i < N) {
        int rp = excl[i] + pref;
        row_ptr[i] = rp;
        cursor[i]  = rp;
    }
    if (b == nb - 1 && t == 0) row_ptr[N] = pref + bsum[b];   // == E
}

__global__ __launch_bounds__(256) void fill_csr(
    const int* __restrict__ src, const int* __restrict__ dst,
    int* __restrict__ cursor, int* __restrict__ csr, int E)
{
    int e = blockIdx.x * 256 + threadIdx.x;
    if (e >= E) return;
    int idx = atomicAdd(&cursor[dst[e]], 1);
    csr[idx] = src[e];
}

// --------------------------- fused SAGE-1 (+ z projection) -----------------
// gather: 2 lane-halves x 4-way unroll = 8 edges in flight per node.
__global__ __launch_bounds__(256) void sage1_fused(
    const float* __restrict__ h, const int* __restrict__ rp, const int* __restrict__ csr,
    const float* __restrict__ s1_self, const float* __restrict__ s1_neigh,
    const float* __restrict__ s1_b, const float* __restrict__ s2_neigh,
    float* __restrict__ h1, float* __restrict__ z16, int N)
{
    __shared__ float aggs[4][32];
    __shared__ float hl[4][64];
    const int t = threadIdx.x;
    const int nb = t >> 6, k = t & 63;
    const int n = blockIdx.x * 4 + nb;
    const int j = k & 31, half = k >> 5;

    int p0 = 0, p1 = 0;
    if (n < N) { p0 = rp[n]; p1 = rp[n + 1]; }
    float a0 = 0.f, a1 = 0.f, a2 = 0.f, a3 = 0.f;
    int p = p0 + half;
    for (; p + 6 < p1; p += 8) {          // edges p, p+2, p+4, p+6 all valid
        int s0 = csr[p], s1 = csr[p + 2], s2 = csr[p + 4], s3 = csr[p + 6];
        a0 += h[(size_t)s0 * 32 + j];
        a1 += h[(size_t)s1 * 32 + j];
        a2 += h[(size_t)s2 * 32 + j];
        a3 += h[(size_t)s3 * 32 + j];
    }
    for (; p < p1; p += 2) a0 += h[(size_t)csr[p] * 32 + j];
    float a = (a0 + a1) + (a2 + a3);
    a += __shfl_down(a, 32);
    if (half == 0) aggs[nb][j] = a;
    __syncthreads();

    float o = 0.f;
    if (n < N) {
        const int nu = __builtin_amdgcn_readfirstlane(n);
        float inv = 1.0f / fmaxf((float)(p1 - p0), 1.0f);
        o = s1_b[k];
#pragma unroll
        for (int jj = 0; jj < 32; ++jj) {
            o = fmaf(h[(size_t)nu * 32 + jj], s1_self[jj * 64 + k], o);
            o = fmaf(aggs[nb][jj] * inv, s1_neigh[jj * 64 + k], o);
        }
        o = fmaxf(o, 0.f);
        h1[(size_t)n * 64 + k] = o;
    }
    hl[nb][k] = o;
    __syncthreads();

    if (n < N && k < 16) {
        float z = 0.f;
        if (k < 10) {
#pragma unroll
            for (int jj = 0; jj < 64; ++jj) z = fmaf(hl[nb][jj], s2_neigh[jj * 10 + k], z);
        }
        z16[(size_t)n * 16 + k] = z;
    }
}

__global__ __launch_bounds__(256) void sage2_final_g(
    const float* __restrict__ h1, const float* __restrict__ z16,
    const int* __restrict__ rp, const int* __restrict__ csr,
    const float* __restrict__ s2_self, const float* __restrict__ s2_b,
    float* __restrict__ out, int N)
{
    int tid = blockIdx.x * 256 + threadIdx.x;
    int nn = tid >> 4, k = tid & 15;
    if (nn >= N || k >= 10) return;
    int p0 = rp[nn], p1 = rp[nn + 1];
    float a0 = 0.f, a1 = 0.f, a2 = 0.f, a3 = 0.f;
    int p = p0;
    for (; p + 4 <= p1; p += 4) {
        int s0 = csr[p], s1 = csr[p + 1], s2 = csr[p + 2], s3 = csr[p + 3];
        a0 += z16[(size_t)s0 * 16 + k];
        a1 += z16[(size_t)s1 * 16 + k];
        a2 += z16[(size_t)s2 * 16 + k];
        a3 += z16[(size_t)s3 * 16 + k];
    }
    for (; p < p1; ++p) a0 += z16[(size_t)csr[p] * 16 + k];
    float inv = 1.0f / fmaxf((float)(p1 - p0), 1.0f);
    float o = s2_b[k] + ((a0 + a1) + (a2 + a3)) * inv;
#pragma unroll
    for (int j = 0; j < 64; ++j) o = fmaf(h1[nn * 64 + j], s2_self[j * 10 + k], o);
    out[nn * 10 + k] = o;
}

extern "C" void kernel_launch(void* const* d_in, const int* in_sizes, int n_in,
                              void* d_out, int out_size, void* d_ws, size_t ws_size,
                              hipStream_t stream)
{
    const float* feat     = (const float*)d_in[0];
    const int*   src      = (const int*)d_in[1];
    const int*   dst      = (const int*)d_in[2];
    const float* conv_w   = (const float*)d_in[3];
    const float* conv_b   = (const float*)d_in[4];
    const float* w1       = (const float*)d_in[5];
    const float* b1       = (const float*)d_in[6];
    const float* w2       = (const float*)d_in[7];
    const float* b2       = (const float*)d_in[8];
    const float* s1_self  = (const float*)d_in[9];
    const float* s1_neigh = (const float*)d_in[10];
    const float* s1_b     = (const float*)d_in[11];
    const float* s2_self  = (const float*)d_in[12];
    const float* s2_neigh = (const float*)d_in[13];
    const float* s2_b     = (const float*)d_in[14];
    float* out = (float*)d_out;

    const int N = in_sizes[0] / 1280;  // 10000
    const int E = in_sizes[1];         // 320000
    const int NB_SCAN = (N + 255) / 256;  // 40

    // ws layout: [row_cnt N][h_fc1 32N]  <- contiguous, zeroed together
    char* wsb = (char*)d_ws;
    int*   row_cnt = (int*)wsb;                      wsb += (size_t)N * 4;
    float* h_fc1   = (float*)wsb;                    wsb += (size_t)N * 32 * 4;
    int*   excl    = (int*)wsb;                      wsb += (size_t)N * 4;
    int*   bsum    = (int*)wsb;                      wsb += 64 * 4;
    int*   row_ptr = (int*)wsb;                      wsb += (size_t)(N + 4) * 4;
    int*   cursor  = (int*)wsb;                      wsb += (size_t)N * 4;
    int*   csr     = (int*)wsb;                      wsb += (size_t)E * 4;
    float* h_cnn   = (float*)wsb;                    wsb += (size_t)N * 32 * 4;
    float* h1      = (float*)wsb;                    wsb += (size_t)N * 64 * 4;
    float* z16     = (float*)wsb;                    wsb += (size_t)N * 16 * 4;
    unsigned char* w1f = (unsigned char*)wsb;

    // zero row_cnt + h_fc1 (contiguous 33N words)
    zero_ws<<<(33 * N + 255) / 256, 256, 0, stream>>>((float*)row_cnt, 33 * N);

    // CSR build (2-kernel scan)
    count_deg<<<(E + 255) / 256, 256, 0, stream>>>(dst, row_cnt, E);
    scan_local<<<NB_SCAN, 256, 0, stream>>>(row_cnt, excl, bsum, N);
    scan_add2<<<NB_SCAN, 256, 0, stream>>>(excl, bsum, row_ptr, cursor, N, NB_SCAN);
    fill_csr<<<(E + 255) / 256, 256, 0, stream>>>(src, dst, cursor, csr, E);

    // CNN (1D grid 2500, XCD-chunked swizzle inside the kernel)
    w1_prep_v4<<<320, 256, 0, stream>>>(w1, w1f);
    cnn_fused_v19<<<(N / 16) * 4, 256, 0, stream>>>(feat, conv_w, conv_b, w1f, h_fc1);
    fc1_finish<<<(N + 7) / 8, 256, 0, stream>>>(h_fc1, b1, w2, b2, h_cnn, N);

    // SAGE 1 (gather + transform + z projection fused)
    sage1_fused<<<(N + 3) / 4, 256, 0, stream>>>(
        h_cnn, row_ptr, csr, s1_self, s1_neigh, s1_b, s2_neigh, h1, z16, N);

    // SAGE 2
    sage2_final_g<<<(int)(((size_t)N * 16 + 255) / 256), 256, 0, stream>>>(
        h1, z16, row_ptr, csr, s2_self, s2_b, out, N);
}

// Round 20
// 181.119 us; speedup vs baseline: 1.1961x; 1.0082x over previous
//
#include <hip/hip_runtime.h>

// ---------------------------------------------------------------------------
// GCN pipeline: CNN(conv3x3+relu+pool2x2+FC1+FC2) -> SAGE(mean) -> SAGE(mean)
// Round 20: R19 + (1) sage2_final 10 threads/node (no idle lanes),
// (2) sage1_fused z-projection split across lane-halves (32 VALU slots
// instead of 64, shfl combine). cnn unchanged.
// ---------------------------------------------------------------------------

typedef __attribute__((ext_vector_type(8)))  short bf16x8;
typedef __attribute__((ext_vector_type(4)))  float f32x4;
typedef __attribute__((ext_vector_type(16))) float f32x16;

__device__ __forceinline__ unsigned short f2bf(float v) {
    union { float f; unsigned int u; } x; x.f = v;
    unsigned int r = x.u + 0x7FFFu + ((x.u >> 16) & 1u);  // RNE
    return (unsigned short)(r >> 16);
}
__device__ __forceinline__ float bf2f(unsigned short b) {
    union { float f; unsigned int u; } x; x.u = ((unsigned int)b) << 16;
    return x.f;
}
__device__ __forceinline__ unsigned cvtpk(float a, float b) {   // low16=bf(a), high16=bf(b)
    unsigned r;
    asm("v_cvt_pk_bf16_f32 %0, %1, %2" : "=v"(r) : "v"(a), "v"(b));
    return r;
}
__device__ __forceinline__ float lo2f(unsigned p) { union { unsigned u; float f; } x; x.u = p << 16; return x.f; }
__device__ __forceinline__ float hi2f(unsigned p) { union { unsigned u; float f; } x; x.u = p & 0xffff0000u; return x.f; }
__device__ __forceinline__ void split_pair(float a, float b, unsigned& hp, unsigned& lp) {
    hp = cvtpk(a, b);
    lp = cvtpk(a - lo2f(hp), b - hi2f(hp));
}

__global__ __launch_bounds__(256) void zero_ws(float* __restrict__ ws, int count) {
    int i = blockIdx.x * 256 + threadIdx.x;
    if (i < count) ws[i] = 0.0f;
}

// ---------------------------------------------------------------------------
// w1 prep (grid 320): fragment-ready bf16 hi/lo image per quarter (ph,qq).
// Within-unit position i maps to pwl: i<4 -> 2i, else 2(i-4)+1.
// ---------------------------------------------------------------------------
__global__ __launch_bounds__(256) void w1_prep_v4(
    const float* __restrict__ w1, unsigned char* __restrict__ w1f)
{
    int gu = blockIdx.x * 256 + threadIdx.x;   // 0..81919
    const int quarter = gu >> 11;
    const int u = gu & 2047;
    const int ph = quarter >> 2, qq = quarter & 3;
    const int ks   = u >> 8;
    const int jh   = (u >> 7) & 1;
    const int part = (u >> 6) & 1;
    const int lane = u & 63;
    const int j    = jh * 16 + (lane & 15);
    const int c    = ks * 4 + (lane >> 4);
    const int k0   = c * 320 + ph * 32 + qq * 8;
    unsigned short v[8];
#pragma unroll
    for (int i = 0; i < 8; ++i) {
        const int pwl_i = (i < 4) ? (2 * i) : (2 * (i - 4) + 1);
        float x = w1[(size_t)(k0 + pwl_i) * 32 + j];
        unsigned short h = f2bf(x);
        v[i] = part ? f2bf(x - bf2f(h)) : h;
    }
    *(uint4*)(w1f + (size_t)quarter * 32768 + (size_t)u * 16) = *(const uint4*)v;
}

// ---------------------------------------------------------------------------
// Fused CNN v19 (unchanged): 16 nodes/block, 256 threads, 1D grid 2500,
// XCD-chunked bijective swizzle, single fc1A, 2 barriers/quarter, bias as
// K=9 tap, direct-b64 pool repack, setprio around MFMA. LDS 34.8KB.
// ---------------------------------------------------------------------------
__global__ __launch_bounds__(256, 4) void cnn_fused_v19(
    const float* __restrict__ feat,
    const float* __restrict__ conv_w, const float* __restrict__ conv_b,
    const unsigned char* __restrict__ w1f,
    float* __restrict__ h_fc1)
{
    __shared__ __align__(16) unsigned char convA[18432];
    __shared__ __align__(16) unsigned char fc1A[16384];   // single buffer

    // ---- XCD-chunked bijective swizzle (nwg=2500, q=312, r=4; m204 form)
    const int orig = blockIdx.x;
    const int c8 = orig & 7;
    const int wgid = (c8 < 4 ? c8 * 313 : 4 * 313 + (c8 - 4) * 312) + (orig >> 3);
    const int xg = wgid >> 2;         // node-group 0..624
    const int qq = wgid & 3;          // column slice 0..3

    const int t = threadIdx.x;
    const int wv = t >> 6;            // 0..3
    const int lane = t & 63;
    const int base = xg * 16;

    const int nn  = lane >> 4;
    const int pwl = lane & 7;
    const int aa  = (lane >> 3) & 1;
    const float* featn = feat + (size_t)(base + wv * 4 + nn) * 1280;

    const int pw = qq * 8 + pwl;      // fixed pooled col
    const int c0 = 2 * pw - 1;        // fixed input col window c0..c0+3
    const bool cv0 = (c0 >= 0);
    const bool cv3 = (c0 + 3 < 64);

    const int cch = lane & 31;
    const int ckg = lane >> 5;        // conv K-group AND output half h
    const int rowr = lane & 31;
    unsigned rsw = (unsigned)(rowr << 4); rsw ^= ((rsw >> 7) & 3u) << 4;

    // conv weight fragments; k=9 carries the bias (A-side k9 input is 1.0)
    bf16x8 cbh, cbl;
    {
        union { unsigned short u[8]; bf16x8 v; } H, L;
#pragma unroll
        for (int i = 0; i < 8; ++i) {
            int k = ckg * 8 + i;
            float x = (k < 9) ? conv_w[cch * 9 + k] : (k == 9 ? conv_b[cch] : 0.0f);
            unsigned short h = f2bf(x);
            H.u[i] = h; L.u[i] = f2bf(x - bf2f(h));
        }
        cbh = H.v; cbl = L.v;
    }

    const int nfr = lane & 15;
    const unsigned hoff = (unsigned)(ckg << 3);   // h*8: within-unit byte offset

    f32x4 acc0 = {0.f, 0.f, 0.f, 0.f};
    f32x4 acc1 = {0.f, 0.f, 0.f, 0.f};
    const f32x16 czero = {};    // hoisted zero C-operand

    float f0[4], f1[4], f2[4];
    auto load_row = [&](int r, float* o) {
        bool rv = (r >= 0) && (r < 20);
        const float* rp = featn + (rv ? r : 0) * 64;
        float2 m = *(const float2*)(rp + c0 + 1);    // c0+1 = 2pw: 8B-aligned, in-bounds
        float v0 = rp[cv0 ? c0 : 0];
        float v3 = rp[cv3 ? (c0 + 3) : 0];
        o[0] = (rv && cv0) ? v0 : 0.f;
        o[1] = rv ? m.x : 0.f;
        o[2] = rv ? m.y : 0.f;
        o[3] = (rv && cv3) ? v3 : 0.f;
    };

    load_row(aa - 1, f0);
    load_row(aa,     f1);
    load_row(aa + 1, f2);

#pragma unroll 1
    for (int ph = 0; ph < 10; ++ph) {
        const int quarter = ph * 4 + qq;
        unsigned char* fbuf = fc1A;

        // ---- (1) FC1 B-frags from global (L2); consumed in phase 4
        const unsigned char* wq = w1f + (size_t)quarter * 32768;
        bf16x8 bF[2][2][2];
#pragma unroll
        for (int si = 0; si < 2; ++si) {
            const int ks = wv + si * 4;
#pragma unroll
            for (int jh = 0; jh < 2; ++jh)
#pragma unroll
                for (int part = 0; part < 2; ++part)
                    bF[si][jh][part] = *(const bf16x8*)(
                        wq + (size_t)((((ks * 2 + jh) * 2 + part)) << 10) + lane * 16);
        }

        // ---- (2) split current rows -> convA + compact tap8
        {
            unsigned P[3][2], Q[3][2];
            split_pair(f0[0], f0[1], P[0][0], Q[0][0]);
            split_pair(f0[2], f0[3], P[0][1], Q[0][1]);
            split_pair(f1[0], f1[1], P[1][0], Q[1][0]);
            split_pair(f1[2], f1[3], P[1][1], Q[1][1]);
            split_pair(f2[0], f2[1], P[2][0], Q[2][0]);
            split_pair(f2[2], f2[3], P[2][1], Q[2][1]);

            const int r0 = pwl * 4 + aa * 2, r1 = r0 + 1;
            unsigned b0 = (unsigned)(r0 << 4); b0 ^= ((b0 >> 7) & 3u) << 4;
            unsigned b1 = (unsigned)(r1 << 4); b1 ^= ((b1 >> 7) & 3u) << 4;
            unsigned char* abw = convA + ((wv * 4 + nn) << 10);
            uint4 H0 = make_uint4(P[0][0],
                                  __builtin_amdgcn_perm(P[1][0], P[0][1], 0x05040100u),
                                  __builtin_amdgcn_perm(P[1][1], P[1][0], 0x05040302u),
                                  P[2][0]);
            uint4 H1 = make_uint4(__builtin_amdgcn_perm(P[0][1], P[0][0], 0x05040302u),
                                  __builtin_amdgcn_perm(P[1][0], P[0][1], 0x07060302u),
                                  P[1][1],
                                  __builtin_amdgcn_perm(P[2][1], P[2][0], 0x05040302u));
            uint4 L0 = make_uint4(Q[0][0],
                                  __builtin_amdgcn_perm(Q[1][0], Q[0][1], 0x05040100u),
                                  __builtin_amdgcn_perm(Q[1][1], Q[1][0], 0x05040302u),
                                  Q[2][0]);
            uint4 L1 = make_uint4(__builtin_amdgcn_perm(Q[0][1], Q[0][0], 0x05040302u),
                                  __builtin_amdgcn_perm(Q[1][0], Q[0][1], 0x07060302u),
                                  Q[1][1],
                                  __builtin_amdgcn_perm(Q[2][1], Q[2][0], 0x05040302u));
            *(uint4*)(abw + b0)       = H0;
            *(uint4*)(abw + b1)       = H1;
            *(uint4*)(abw + 512 + b0) = L0;
            *(uint4*)(abw + 512 + b1) = L1;
            unsigned wr0 = __builtin_amdgcn_perm(Q[2][1], P[2][1], 0x05040100u);
            unsigned wr1 = __builtin_amdgcn_perm(Q[2][1], P[2][1], 0x07060302u);
            *(uint2*)(convA + 16384 + (((wv * 4 + nn) * 32 + r0) << 2)) = make_uint2(wr0, wr1);
        }

        // ---- (2b) rotate window + prefetch next ph's two new rows
        if (ph < 9) {
#pragma unroll
            for (int j = 0; j < 4; ++j) f0[j] = f2[j];
            load_row(2 * ph + 2 + aa, f1);
            load_row(2 * ph + 3 + aa, f2);
        }

        // ---- (3) conv MFMA + in-lane pool + direct-b64 repack into fc1A
#pragma unroll
        for (int nn2 = 0; nn2 < 4; ++nn2) {
            bf16x8 a_h, a_l;
            if (ckg == 0) {
                const unsigned char* ab = convA + ((wv * 4 + nn2) << 10);
                a_h = *(const bf16x8*)(ab + rsw);
                a_l = *(const bf16x8*)(ab + 512 + rsw);
            } else {
                unsigned cw = *(const unsigned*)(convA + 16384 + (((wv * 4 + nn2) * 32 + rowr) << 2));
                // k=8: tap8 (hi/lo); k=9: constant 1.0 (bias tap; bf16(1.0)=0x3F80)
                a_h = (bf16x8){(short)(cw & 0xffffu), (short)0x3F80, 0, 0, 0, 0, 0, 0};
                a_l = (bf16x8){(short)(cw >> 16),     0,             0, 0, 0, 0, 0, 0};
            }
            f32x16 ca;
            __builtin_amdgcn_s_setprio(1);
            ca = __builtin_amdgcn_mfma_f32_32x32x16_bf16(a_l, cbh, czero, 0, 0, 0);
            ca = __builtin_amdgcn_mfma_f32_32x32x16_bf16(a_h, cbl, ca, 0, 0, 0);
            ca = __builtin_amdgcn_mfma_f32_32x32x16_bf16(a_h, cbh, ca, 0, 0, 0);
            __builtin_amdgcn_s_setprio(0);

            float pv0 = fmaxf(fmaxf(fmaxf(ca[0],  ca[1]),  fmaxf(ca[2],  ca[3])),  0.f);
            float pv1 = fmaxf(fmaxf(fmaxf(ca[4],  ca[5]),  fmaxf(ca[6],  ca[7])),  0.f);
            float pv2 = fmaxf(fmaxf(fmaxf(ca[8],  ca[9]),  fmaxf(ca[10], ca[11])), 0.f);
            float pv3 = fmaxf(fmaxf(fmaxf(ca[12], ca[13]), fmaxf(ca[14], ca[15])), 0.f);

            unsigned ha, la, hb, lb;
            split_pair(pv0, pv1, ha, la);
            split_pair(pv2, pv3, hb, lb);

            const int nloc = wv * 4 + nn2;
            const int ksW = cch >> 2, kgW = cch & 3;
            unsigned bh = (unsigned)((((0 * 8 + ksW) * 64) + kgW * 16 + nloc) << 4);
            bh ^= ((bh >> 8) & 7u) << 4;
            unsigned bl = (unsigned)((((1 * 8 + ksW) * 64) + kgW * 16 + nloc) << 4);
            bl ^= ((bl >> 8) & 7u) << 4;
            *(uint2*)(fbuf + bh + hoff) = make_uint2(ha, hb);
            *(uint2*)(fbuf + bl + hoff) = make_uint2(la, lb);
        }

        __syncthreads();   // fc1A writes visible to all waves

        // ---- (4) FC1 MFMA: wave wv handles ksteps {wv, wv+4}
        __builtin_amdgcn_s_setprio(1);
#pragma unroll
        for (int si = 0; si < 2; ++si) {
            const int ks = wv + si * 4;
            unsigned bH = (unsigned)(((0 * 8 + ks) << 10) + lane * 16); bH ^= ((bH >> 8) & 7u) << 4;
            unsigned bL = (unsigned)(((1 * 8 + ks) << 10) + lane * 16); bL ^= ((bL >> 8) & 7u) << 4;
            bf16x8 fa_h = *(const bf16x8*)(fbuf + bH);
            bf16x8 fa_l = *(const bf16x8*)(fbuf + bL);
            acc0 = __builtin_amdgcn_mfma_f32_16x16x32_bf16(fa_l, bF[si][0][0], acc0, 0, 0, 0);
            acc0 = __builtin_amdgcn_mfma_f32_16x16x32_bf16(fa_h, bF[si][0][1], acc0, 0, 0, 0);
            acc0 = __builtin_amdgcn_mfma_f32_16x16x32_bf16(fa_h, bF[si][0][0], acc0, 0, 0, 0);
            acc1 = __builtin_amdgcn_mfma_f32_16x16x32_bf16(fa_l, bF[si][1][0], acc1, 0, 0, 0);
            acc1 = __builtin_amdgcn_mfma_f32_16x16x32_bf16(fa_h, bF[si][1][1], acc1, 0, 0, 0);
            acc1 = __builtin_amdgcn_mfma_f32_16x16x32_bf16(fa_h, bF[si][1][0], acc1, 0, 0, 0);
        }
        __builtin_amdgcn_s_setprio(0);

        __syncthreads();   // all waves done reading fc1A before next quarter's writes
    }

    // ---- epilogue: cross-wave reduce (overlay on convA) + atomic FC1 partials
    float* red = (float*)convA;
#pragma unroll
    for (int r = 0; r < 4; ++r) {
        int node = (lane >> 4) * 4 + r;
        red[wv * 512 + node * 32 + nfr]      = acc0[r];
        red[wv * 512 + node * 32 + 16 + nfr] = acc1[r];
    }
    __syncthreads();
    {
        const int en = t >> 4, jp = t & 15;
        const int j0 = 2 * jp;
        float s0 = 0.f, s1 = 0.f;
#pragma unroll
        for (int wi = 0; wi < 4; ++wi) {
            s0 += red[wi * 512 + en * 32 + j0];
            s1 += red[wi * 512 + en * 32 + j0 + 1];
        }
        atomicAdd(&h_fc1[(size_t)(base + en) * 32 + j0],     s0);
        atomicAdd(&h_fc1[(size_t)(base + en) * 32 + j0 + 1], s1);
    }
}

// h_fc1 -> +b1, relu, FC2(+b2), relu -> h_cnn
__global__ __launch_bounds__(256) void fc1_finish(
    const float* __restrict__ h_fc1, const float* __restrict__ b1,
    const float* __restrict__ w2, const float* __restrict__ b2,
    float* __restrict__ h_out, int N)
{
    __shared__ float hr[8][32];
    const int t = threadIdx.x;
    const int nb = t >> 5, j = t & 31;
    const int n = blockIdx.x * 8 + nb;
    if (n < N) hr[nb][j] = fmaxf(h_fc1[(size_t)n * 32 + j] + b1[j], 0.f);
    __syncthreads();
    if (n >= N) return;
    float o = b2[j];
#pragma unroll
    for (int k = 0; k < 32; ++k) o = fmaf(hr[nb][k], w2[k * 32 + j], o);
    h_out[(size_t)n * 32 + j] = fmaxf(o, 0.f);
}

// --------------------------- CSR build -------------------------------------
__global__ __launch_bounds__(256) void count_deg(
    const int* __restrict__ dst, int* __restrict__ cnt, int E)
{
    int e = blockIdx.x * 256 + threadIdx.x;
    if (e < E) atomicAdd(&cnt[dst[e]], 1);
}

__global__ __launch_bounds__(256) void scan_local(
    const int* __restrict__ cnt, int* __restrict__ excl, int* __restrict__ bsum, int N)
{
    __shared__ int s[256];
    int t = threadIdx.x, b = blockIdx.x, i = b * 256 + t;
    int v = (i < N) ? cnt[i] : 0;
    s[t] = v;
    __syncthreads();
#pragma unroll
    for (int off = 1; off < 256; off <<= 1) {
        int x = (t >= off) ? s[t - off] : 0;
        __syncthreads();
        s[t] += x;
        __syncthreads();
    }
    int incl = s[t];
    if (i < N) excl[i] = incl - v;
    if (t == 255) bsum[b] = incl;
}

// scan_add with in-block bsum prefix
__global__ __launch_bounds__(256) void scan_add2(
    const int* __restrict__ excl, const int* __restrict__ bsum,
    int* __restrict__ row_ptr, int* __restrict__ cursor, int N, int nb)
{
    __shared__ int spref;
    const int t = threadIdx.x, b = blockIdx.x;
    if (t < 64) {
        int v = (t < b) ? bsum[t] : 0;   // nb <= 64
#pragma unroll
        for (int off = 32; off > 0; off >>= 1) v += __shfl_down(v, off);
        if (t == 0) spref = v;
    }
    __syncthreads();
    const int pref = spref;
    int i = b * 256 + t;
    if (i < N) {
        int rp = excl[i] + pref;
        row_ptr[i] = rp;
        cursor[i]  = rp;
    }
    if (b == nb - 1 && t == 0) row_ptr[N] = pref + bsum[b];   // == E
}

__global__ __launch_bounds__(256) void fill_csr(
    const int* __restrict__ src, const int* __restrict__ dst,
    int* __restrict__ cursor, int* __restrict__ csr, int E)
{
    int e = blockIdx.x * 256 + threadIdx.x;
    if (e >= E) return;
    int idx = atomicAdd(&cursor[dst[e]], 1);
    csr[idx] = src[e];
}

// --------------------------- fused SAGE-1 (+ z projection) -----------------
// gather: 2 lane-halves x 4-way unroll = 8 edges in flight per node.
// z projection: jj-loop split across lane-halves (32 slots), shfl combine.
__global__ __launch_bounds__(256) void sage1_fused(
    const float* __restrict__ h, const int* __restrict__ rp, const int* __restrict__ csr,
    const float* __restrict__ s1_self, const float* __restrict__ s1_neigh,
    const float* __restrict__ s1_b, const float* __restrict__ s2_neigh,
    float* __restrict__ h1, float* __restrict__ z16, int N)
{
    __shared__ float aggs[4][32];
    __shared__ float hl[4][64];
    const int t = threadIdx.x;
    const int nb = t >> 6, k = t & 63;
    const int n = blockIdx.x * 4 + nb;
    const int j = k & 31, half = k >> 5;

    int p0 = 0, p1 = 0;
    if (n < N) { p0 = rp[n]; p1 = rp[n + 1]; }
    float a0 = 0.f, a1 = 0.f, a2 = 0.f, a3 = 0.f;
    int p = p0 + half;
    for (; p + 6 < p1; p += 8) {          // edges p, p+2, p+4, p+6 all valid
        int s0 = csr[p], s1 = csr[p + 2], s2 = csr[p + 4], s3 = csr[p + 6];
        a0 += h[(size_t)s0 * 32 + j];
        a1 += h[(size_t)s1 * 32 + j];
        a2 += h[(size_t)s2 * 32 + j];
        a3 += h[(size_t)s3 * 32 + j];
    }
    for (; p < p1; p += 2) a0 += h[(size_t)csr[p] * 32 + j];
    float a = (a0 + a1) + (a2 + a3);
    a += __shfl_down(a, 32);
    if (half == 0) aggs[nb][j] = a;
    __syncthreads();

    float o = 0.f;
    if (n < N) {
        const int nu = __builtin_amdgcn_readfirstlane(n);
        float inv = 1.0f / fmaxf((float)(p1 - p0), 1.0f);
        o = s1_b[k];
#pragma unroll
        for (int jj = 0; jj < 32; ++jj) {
            o = fmaf(h[(size_t)nu * 32 + jj], s1_self[jj * 64 + k], o);
            o = fmaf(aggs[nb][jj] * inv, s1_neigh[jj * 64 + k], o);
        }
        o = fmaxf(o, 0.f);
        h1[(size_t)n * 64 + k] = o;
    }
    hl[nb][k] = o;
    __syncthreads();

    // z projection: lane (half,kk) computes half the jj sum for output kk
    {
        const int kk = k & 31;            // kk<10 active (both halves)
        float z = 0.f;
        if (n < N && kk < 10) {
            const int jbase = half * 32;
#pragma unroll
            for (int jj = 0; jj < 32; ++jj)
                z = fmaf(hl[nb][jbase + jj], s2_neigh[(jbase + jj) * 10 + kk], z);
        }
        z += __shfl_down(z, 32);
        if (n < N && half == 0 && kk < 10)
            z16[(size_t)n * 16 + kk] = z;
    }
}

// 10 threads per node (k = 0..9), no idle lanes
__global__ __launch_bounds__(256) void sage2_final_g(
    const float* __restrict__ h1, const float* __restrict__ z16,
    const int* __restrict__ rp, const int* __restrict__ csr,
    const float* __restrict__ s2_self, const float* __restrict__ s2_b,
    float* __restrict__ out, int N)
{
    int tid = blockIdx.x * 256 + threadIdx.x;
    int nn = tid / 10;                  // magic-mul div
    int k = tid - nn * 10;
    if (nn >= N) return;
    int p0 = rp[nn], p1 = rp[nn + 1];
    float a0 = 0.f, a1 = 0.f, a2 = 0.f, a3 = 0.f;
    int p = p0;
    for (; p + 4 <= p1; p += 4) {
        int s0 = csr[p], s1 = csr[p + 1], s2 = csr[p + 2], s3 = csr[p + 3];
        a0 += z16[(size_t)s0 * 16 + k];
        a1 += z16[(size_t)s1 * 16 + k];
        a2 += z16[(size_t)s2 * 16 + k];
        a3 += z16[(size_t)s3 * 16 + k];
    }
    for (; p < p1; ++p) a0 += z16[(size_t)csr[p] * 16 + k];
    float inv = 1.0f / fmaxf((float)(p1 - p0), 1.0f);
    float o = s2_b[k] + ((a0 + a1) + (a2 + a3)) * inv;
#pragma unroll
    for (int j = 0; j < 64; ++j) o = fmaf(h1[nn * 64 + j], s2_self[j * 10 + k], o);
    out[nn * 10 + k] = o;
}

extern "C" void kernel_launch(void* const* d_in, const int* in_sizes, int n_in,
                              void* d_out, int out_size, void* d_ws, size_t ws_size,
                              hipStream_t stream)
{
    const float* feat     = (const float*)d_in[0];
    const int*   src      = (const int*)d_in[1];
    const int*   dst      = (const int*)d_in[2];
    const float* conv_w   = (const float*)d_in[3];
    const float* conv_b   = (const float*)d_in[4];
    const float* w1       = (const float*)d_in[5];
    const float* b1       = (const float*)d_in[6];
    const float* w2       = (const float*)d_in[7];
    const float* b2       = (const float*)d_in[8];
    const float* s1_self  = (const float*)d_in[9];
    const float* s1_neigh = (const float*)d_in[10];
    const float* s1_b     = (const float*)d_in[11];
    const float* s2_self  = (const float*)d_in[12];
    const float* s2_neigh = (const float*)d_in[13];
    const float* s2_b     = (const float*)d_in[14];
    float* out = (float*)d_out;

    const int N = in_sizes[0] / 1280;  // 10000
    const int E = in_sizes[1];         // 320000
    const int NB_SCAN = (N + 255) / 256;  // 40

    // ws layout: [row_cnt N][h_fc1 32N]  <- contiguous, zeroed together
    char* wsb = (char*)d_ws;
    int*   row_cnt = (int*)wsb;                      wsb += (size_t)N * 4;
    float* h_fc1   = (float*)wsb;                    wsb += (size_t)N * 32 * 4;
    int*   excl    = (int*)wsb;                      wsb += (size_t)N * 4;
    int*   bsum    = (int*)wsb;                      wsb += 64 * 4;
    int*   row_ptr = (int*)wsb;                      wsb += (size_t)(N + 4) * 4;
    int*   cursor  = (int*)wsb;                      wsb += (size_t)N * 4;
    int*   csr     = (int*)wsb;                      wsb += (size_t)E * 4;
    float* h_cnn   = (float*)wsb;                    wsb += (size_t)N * 32 * 4;
    float* h1      = (float*)wsb;                    wsb += (size_t)N * 64 * 4;
    float* z16     = (float*)wsb;                    wsb += (size_t)N * 16 * 4;
    unsigned char* w1f = (unsigned char*)wsb;

    // zero row_cnt + h_fc1 (contiguous 33N words)
    zero_ws<<<(33 * N + 255) / 256, 256, 0, stream>>>((float*)row_cnt, 33 * N);

    // CSR build (2-kernel scan)
    count_deg<<<(E + 255) / 256, 256, 0, stream>>>(dst, row_cnt, E);
    scan_local<<<NB_SCAN, 256, 0, stream>>>(row_cnt, excl, bsum, N);
    scan_add2<<<NB_SCAN, 256, 0, stream>>>(excl, bsum, row_ptr, cursor, N, NB_SCAN);
    fill_csr<<<(E + 255) / 256, 256, 0, stream>>>(src, dst, cursor, csr, E);

    // CNN (1D grid 2500, XCD-chunked swizzle inside the kernel)
    w1_prep_v4<<<320, 256, 0, stream>>>(w1, w1f);
    cnn_fused_v19<<<(N / 16) * 4, 256, 0, stream>>>(feat, conv_w, conv_b, w1f, h_fc1);
    fc1_finish<<<(N + 7) / 8, 256, 0, stream>>>(h_fc1, b1, w2, b2, h_cnn, N);

    // SAGE 1 (gather + transform + z projection fused)
    sage1_fused<<<(N + 3) / 4, 256, 0, stream>>>(
        h_cnn, row_ptr, csr, s1_self, s1_neigh, s1_b, s2_neigh, h1, z16, N);

    // SAGE 2
    sage2_final_g<<<(int)(((size_t)N * 10 + 255) / 256), 256, 0, stream>>>(
        h1, z16, row_ptr, csr, s2_self, s2_b, out, N);
}